// Round 15
// baseline (625.407 us; speedup 1.0000x reference)
//
#include <hip/hip_runtime.h>

#define BB 32
#define CKD 64
#define CC 8
#define KK 8
#define FPW 132   // u32 pitch for packed V-staging

// level tables (compile-time; N=8192, 13 levels)
__device__ const int D_KBS[13] = {128,64,32,16,8,4,2,1,1,1,1,1,1};            // 32-t kb count per level
__device__ const int D_PVP[13] = {0,128,192,224,240,248,252,254,255,256,257,258,259}; // pv kb prefix
__device__ const int D_TB[14] = {0,64,96,112,120,124,126,127,128,129,130,131,132,133}; // inv 64-t tile prefix
__device__ const int D_FTOF[13] = {0,524288,786432,917504,983040,1015808,1032192,
                                   1048576,1064960,1081344,1097728,1114112,1130496}; // fwd table elem offsets
// mix x-major prefix
__device__ const int D_XP[65] = {0,13,25,36,46,56,65,74,83,92,100,108,116,124,132,140,
    148,156,163,170,177,184,191,198,205,212,219,226,233,240,247,254,261,268,274,280,
    286,292,298,304,310,316,322,328,334,340,346,352,358,364,370,376,382,388,394,400,
    406,412,418,424,430,436,442,448,454};

typedef __attribute__((ext_vector_type(4))) short s4v;
typedef __attribute__((ext_vector_type(8))) short s8v;
typedef __attribute__((ext_vector_type(4))) float f4v;

static __device__ __forceinline__ float4 ld4(const float* p){ return *(const float4*)p; }
static __device__ __forceinline__ size_t d_udo(int i){ return 33554432ull - (16777216u >> i); }
static __device__ __forceinline__ size_t d_uso(int i){ return 50329600ull - (16777216u >> i); }
static __device__ __forceinline__ size_t d_tof(int i){ return 128ull * (8192u - (8192u >> i)); }

static __device__ __forceinline__ unsigned short b16(float f) {
    unsigned u = __float_as_uint(f);
    u += 0x7FFFu + ((u >> 16) & 1u);      // RNE
    return (unsigned short)(u >> 16);
}
static __device__ __forceinline__ float fb16(unsigned short h) {
    return __uint_as_float(((unsigned)h) << 16);
}
static __device__ __forceinline__ unsigned packhl(float f) {
    unsigned u = __float_as_uint(f);
    unsigned hi = u & 0xFFFF0000u;        // truncation split
    float r = f - __uint_as_float(hi);
    unsigned lo = __float_as_uint(r) & 0xFFFF0000u;
    return (hi >> 16) | lo;
}

// ---------------- combined trig-table generation (z=0: inv T, z=1: fwd F frag-ordered)
__global__ __launch_bounds__(256) void gen_tbl2_k(unsigned short* __restrict__ Th,
        unsigned short* __restrict__ Tl, unsigned short* __restrict__ Tfh,
        unsigned short* __restrict__ Tfl) {
    int lvl = blockIdx.y;
    int nh = 4096 >> lvl;
    int idx = blockIdx.x * 256 + threadIdx.x;
    if (blockIdx.z == 0) {
        if (idx >= nh * 128) return;
        int t = idx >> 7, k = idx & 127, x = k >> 1;
        int l = nh / 2 + 1; if (l > 64) l = 64;
        float v = 0.f;
        if (x < l) {
            int r = (x * t) & (nh - 1);
            float th = 6.283185307179586f * ((float)r / (float)nh);
            float s, c; sincosf(th, &s, &c);
            v = (k & 1) ? s : c;
        }
        unsigned short hi = b16(v);
        unsigned short lo = b16(v - fb16(hi));
        size_t off = d_tof(lvl) + idx;
        Th[off] = hi; Tl[off] = lo;
    } else {
        int nhp = nh < 128 ? 128 : nh;
        if (idx >= 128 * nhp) return;
        int j = idx & 7;
        int lane = (idx >> 3) & 63;
        int mt = (idx >> 9) & 7;
        int kb = idx >> 12;
        int row = mt*16 + (lane & 15);
        int t = kb*32 + (lane >> 4)*8 + j;
        int x = row >> 1;
        int l = nh / 2 + 1; if (l > 64) l = 64;
        float v = 0.f;
        if (x < l && t < nh) {
            int r = (x * t) & (nh - 1);
            float th = 6.283185307179586f * ((float)r / (float)nh);
            float s, c; sincosf(th, &s, &c);
            v = (row & 1) ? -s : c;
        }
        unsigned short hi = b16(v);
        unsigned short lo = b16(v - fb16(hi));
        size_t off = (size_t)D_FTOF[lvl] + idx;
        Tfh[off] = hi; Tfl[off] = lo;
    }
}

// ---------------- W transpose: wt[arr][x][i*64+o] = W_arr[(i*64+o)*64 + x]
__global__ __launch_bounds__(256) void wtr_k(const float* __restrict__ wAr,
        const float* __restrict__ wAi, const float* __restrict__ wBr,
        const float* __restrict__ wBi, const float* __restrict__ wCr,
        const float* __restrict__ wCi, float* __restrict__ wt) {
    int x = blockIdx.x, arr = blockIdx.y;
    const float* W;
    switch (arr) {
        case 0: W = wAr; break;
        case 1: W = wAi; break;
        case 2: W = wBr; break;
        case 3: W = wBi; break;
        case 4: W = wCr; break;
        default: W = wCi; break;
    }
    float* o = wt + ((size_t)arr*64 + x)*4096;
    for (int q = threadIdx.x; q < 4096; q += 256)
        o[q] = W[(size_t)q*64 + x];
}

// ---------------- big mixing matrix, FRAGMENT-ORDERED bf16 hi/lo, signs/zeros folded.
__global__ __launch_bounds__(256) void wbig_k(const float* __restrict__ wt,
        unsigned short* __restrict__ wbh, unsigned short* __restrict__ wbl) {
    int x = blockIdx.x;
    int f0 = blockIdx.y * 2048;
    for (int q = threadIdx.x; q < 2048; q += 256) {
        int f = f0 + q;
        int j = f & 7;
        int lane = (f >> 3) & 63;
        int nt = (f >> 9) & 15;
        int kt = f >> 13;
        int k = kt*32 + (lane >> 4)*8 + j;
        int n = nt*16 + (lane & 15);
        int pk = k >> 6, i = k & 63;
        int pn = n >> 6, o = n & 63;
        int arr; float sgn;
        switch ((pn << 2) | pk) {
            case 0:  arr = 0; sgn =  1.f; break;
            case 1:  arr = 1; sgn = -1.f; break;
            case 2:  arr = 2; sgn =  1.f; break;
            case 3:  arr = 3; sgn = -1.f; break;
            case 4:  arr = 1; sgn = -1.f; break;
            case 5:  arr = 0; sgn = -1.f; break;
            case 6:  arr = 3; sgn = -1.f; break;
            case 7:  arr = 2; sgn = -1.f; break;
            case 8:  arr = 4; sgn =  1.f; break;
            case 9:  arr = 5; sgn = -1.f; break;
            case 12: arr = 5; sgn = -1.f; break;
            case 13: arr = 4; sgn = -1.f; break;
            default: arr = -1; sgn = 0.f; break;
        }
        float v = 0.f;
        if (arr >= 0) v = sgn * wt[((size_t)arr*64 + x)*4096 + (size_t)i*64 + o];
        unsigned short h = b16(v);
        unsigned short l2 = b16(v - fb16(h));
        wbh[(size_t)x*65536 + f] = h;
        wbl[(size_t)x*65536 + f] = l2;
    }
}

// ---------------- decompose (big levels 0..4): writes s fp32 (chain) + packed frag pv (d,s).
// grid (nh/128 chunks, 32 b); fp32 d is never written (dead — inv overwrites the slot).
__global__ __launch_bounds__(256) void decomp_k(const float* __restrict__ xin,
        const float* __restrict__ ecd, const float* __restrict__ ecs,
        float* __restrict__ sslot, unsigned* __restrict__ pvL,
        int nh, int kbs) {
    __shared__ unsigned vd[64*FPW];   // packed d [i][t] swizzled (33.8 KB)
    __shared__ unsigned vs[64*FPW];   // packed s
    int chunk = blockIdx.x, b = blockIdx.y;
    int t0 = chunk * 128;
    int tid = threadIdx.x;
    #pragma unroll
    for (int wi = 0; wi < 4; wi++) {
        int q = tid + wi*256;            // 1024 = 128 t x 8 c
        int c = q & 7, tl = q >> 3;
        int t = t0 + tl;
        const float* p0 = xin + ((size_t)b*2*nh + 2*t)*CKD + c*KK;
        float xa[16];
        float4 v;
        v = ld4(p0);      xa[0]=v.x; xa[1]=v.y; xa[2]=v.z; xa[3]=v.w;
        v = ld4(p0+4);    xa[4]=v.x; xa[5]=v.y; xa[6]=v.z; xa[7]=v.w;
        v = ld4(p0+64);   xa[8]=v.x; xa[9]=v.y; xa[10]=v.z; xa[11]=v.w;
        v = ld4(p0+68);   xa[12]=v.x; xa[13]=v.y; xa[14]=v.z; xa[15]=v.w;
        float dd[8], ss[8];
        #pragma unroll
        for (int m = 0; m < 8; m++) { dd[m] = 0.f; ss[m] = 0.f; }
        #pragma unroll
        for (int j = 0; j < 16; j++) {
            float xv = xa[j];
            #pragma unroll
            for (int m = 0; m < 8; m++) {
                dd[m] = fmaf(xv, ecd[j*8+m], dd[m]);
                ss[m] = fmaf(xv, ecs[j*8+m], ss[m]);
            }
        }
        float* sp = sslot + ((size_t)b*nh + t)*CKD + c*KK;
        *(float4*)sp     = make_float4(ss[0],ss[1],ss[2],ss[3]);
        *(float4*)(sp+4) = make_float4(ss[4],ss[5],ss[6],ss[7]);
        #pragma unroll
        for (int j = 0; j < 8; j++) {
            int row = c*8 + j;
            int cw = tl ^ (((row >> 3) & 7) << 2);
            vd[row*FPW + cw] = packhl(dd[j]);
            vs[row*FPW + cw] = packhl(ss[j]);
        }
    }
    __syncthreads();
    unsigned* P = pvL + (size_t)b*kbs*4096;
    #pragma unroll
    for (int qq = 0; qq < 16; qq++) {
        int fi = tid + 256*qq;           // 4096 uint4 granules = 2 z x 2048
        int z = fi >> 11;
        int rem = fi & 2047;
        int j4 = rem & 1;
        int lane2 = (rem >> 1) & 63;
        int nt = (rem >> 7) & 3;
        int kbl = rem >> 9;
        int kbg = chunk*4 + kbl;
        int lrow = nt*16 + (lane2 & 15);
        int cb = kbl*32 + (lane2 >> 4)*8 + j4*4;
        int rsw = ((lrow >> 3) & 7) << 2;
        const unsigned* src = z ? vs : vd;
        uint4 v = *(const uint4*)&src[lrow*FPW + (cb ^ rsw)];
        *(uint4*)(P + (((size_t)(kbg*8 + z*4 + nt))*64 + lane2)*8 + j4*4) = v;
    }
}

// ---------------- fused decompose levels 5..12 (+T0): all in LDS; emits packed frag pv only.
__global__ __launch_bounds__(256) void decomp_small_k(const float* __restrict__ s4base,
        const float* __restrict__ ecd, const float* __restrict__ ecs,
        const float* __restrict__ T0w, const float* __restrict__ T0b,
        unsigned* __restrict__ pv, float* __restrict__ xt0) {
    __shared__ float sA[128*64];      // 32 KB
    __shared__ float sB[64*64];       // 16 KB
    __shared__ unsigned sDp[128*64];  // 32 KB packed d [t][i]
    int b = blockIdx.x, tid = threadIdx.x;
    for (int lvl = 5; lvl <= 12; lvl++) {
        int nh = 4096 >> lvl;
        const float* src = (lvl == 5) ? (s4base + (size_t)b*256*CKD)
                                      : (((lvl - 6) & 1) ? sB : sA);
        float* dst = ((lvl - 5) & 1) ? sB : sA;
        for (int q = tid; q < nh*8; q += 256) {
            int c = q & 7, t = q >> 3;
            const float* p0 = src + (size_t)(2*t)*CKD + c*KK;
            float xa[16];
            float4 v;
            v = ld4(p0);      xa[0]=v.x; xa[1]=v.y; xa[2]=v.z; xa[3]=v.w;
            v = ld4(p0+4);    xa[4]=v.x; xa[5]=v.y; xa[6]=v.z; xa[7]=v.w;
            v = ld4(p0+64);   xa[8]=v.x; xa[9]=v.y; xa[10]=v.z; xa[11]=v.w;
            v = ld4(p0+68);   xa[12]=v.x; xa[13]=v.y; xa[14]=v.z; xa[15]=v.w;
            float dd[8], ss[8];
            #pragma unroll
            for (int m = 0; m < 8; m++) { dd[m] = 0.f; ss[m] = 0.f; }
            #pragma unroll
            for (int j = 0; j < 16; j++) {
                float xv = xa[j];
                #pragma unroll
                for (int m = 0; m < 8; m++) {
                    dd[m] = fmaf(xv, ecd[j*8+m], dd[m]);
                    ss[m] = fmaf(xv, ecs[j*8+m], ss[m]);
                }
            }
            float* dl = dst + t*CKD + c*KK;
            unsigned* dp = sDp + t*CKD + c*KK;
            #pragma unroll
            for (int j = 0; j < 8; j++) {
                dl[j] = ss[j];
                dp[j] = packhl(dd[j]);
            }
        }
        __syncthreads();
        // fragment store to pv (d from sDp, s packed from dst)
        int kbs = D_KBS[lvl];
        unsigned* P = pv + (size_t)D_PVP[lvl]*131072 + (size_t)b*kbs*4096;
        for (int f = tid; f < kbs*512; f += 256) {
            int lane = f & 63;
            int zn = (f >> 6) & 7;
            int kb = f >> 9;
            int z = zn >> 2, nt = zn & 3;
            int i = nt*16 + (lane & 15);
            int tb2 = kb*32 + (lane >> 4)*8;
            unsigned vals[8];
            #pragma unroll
            for (int j = 0; j < 8; j++) {
                int t = tb2 + j;
                vals[j] = z ? packhl(dst[t*CKD + i]) : sDp[t*CKD + i];
            }
            unsigned* pp = P + (((size_t)(kb*8 + z*4 + nt))*64 + lane)*8;
            *(uint4*)pp     = make_uint4(vals[0],vals[1],vals[2],vals[3]);
            *(uint4*)(pp+4) = make_uint4(vals[4],vals[5],vals[6],vals[7]);
        }
        __syncthreads();
    }
    // T0 linear on s12 (row 0 of sB)
    if (tid < 64) {
        int m = tid & 7, c = tid >> 3;
        const float* xr = sB + c*KK;
        float a = T0b[m];
        #pragma unroll
        for (int j = 0; j < 8; j++) a = fmaf(xr[j], T0w[m*8+j], a);
        xt0[(size_t)b*64 + tid] = a;
    }
}

// ---------------- forward truncated DFT via MFMA, LDS-FREE, FULL-K per block.
// grid (13 lvl, 32 b); direct xf_all write; no partials, no reduce.
__global__ __launch_bounds__(256) void fft_fwd_mfma_k(const unsigned* __restrict__ pv,
        const unsigned short* __restrict__ Tfh, const unsigned short* __restrict__ Tfl,
        float2* __restrict__ xf_all) {
    int lvl = blockIdx.x;
    int kbs = D_KBS[lvl];
    int b = blockIdx.y;
    const unsigned* PV = pv + (size_t)D_PVP[lvl]*131072 + (size_t)b*kbs*4096;
    const unsigned short* THb = Tfh + D_FTOF[lvl];
    const unsigned short* TLb = Tfl + D_FTOF[lvl];
    int tid = threadIdx.x;
    int w = tid >> 6, lane = tid & 63;
    int col = lane & 15, khi = lane >> 4;
    int mt0 = w * 2;                        // wave handles m-tiles {2w, 2w+1}
    f4v acc[2][8];
    #pragma unroll
    for (int m = 0; m < 2; m++)
        #pragma unroll
        for (int n = 0; n < 8; n++) acc[m][n] = (f4v){0.f,0.f,0.f,0.f};
    for (int kb = 0; kb < kbs; kb++) {
        s8v ah[2], al[2];
        #pragma unroll
        for (int m = 0; m < 2; m++) {
            size_t fo = (((size_t)kb*8 + (mt0 + m))*64 + lane)*8;   // lane-contiguous
            ah[m] = *(const s8v*)(THb + fo);
            al[m] = *(const s8v*)(TLb + fo);
        }
        #pragma unroll
        for (int n = 0; n < 8; n++) {
            const unsigned* bp = PV + (((size_t)(kb*8 + n))*64 + lane)*8;
            uint4 w0 = *(const uint4*)bp;
            uint4 w1 = *(const uint4*)(bp + 4);
            s8v bh, bl;
            const unsigned* pw = &w0.x;
            #pragma unroll
            for (int j = 0; j < 4; j++) {
                bh[j] = (short)(pw[j] & 0xFFFFu);
                bl[j] = (short)(pw[j] >> 16);
            }
            pw = &w1.x;
            #pragma unroll
            for (int j = 0; j < 4; j++) {
                bh[4+j] = (short)(pw[j] & 0xFFFFu);
                bl[4+j] = (short)(pw[j] >> 16);
            }
            #pragma unroll
            for (int m = 0; m < 2; m++) {
                acc[m][n] = __builtin_amdgcn_mfma_f32_16x16x32_bf16(ah[m], bh, acc[m][n], 0,0,0);
                acc[m][n] = __builtin_amdgcn_mfma_f32_16x16x32_bf16(ah[m], bl, acc[m][n], 0,0,0);
                acc[m][n] = __builtin_amdgcn_mfma_f32_16x16x32_bf16(al[m], bh, acc[m][n], 0,0,0);
            }
        }
    }
    float* XB = (float*)xf_all + (size_t)lvl*524288 + (size_t)b*16384;
    #pragma unroll
    for (int m = 0; m < 2; m++) {
        int m0 = (mt0 + m)*16 + khi*4;
        #pragma unroll
        for (int n = 0; n < 8; n++) {
            int ic = n*16 + col;
            int z = ic >> 6, i = ic & 63;
            float* X = XB + (size_t)z*8192;
            #pragma unroll
            for (int r = 0; r < 4; r++) {
                int row = m0 + r;
                X[(((size_t)(row >> 1)*64 + i) << 1) | (row & 1)] = acc[m][n][r];
            }
        }
    }
}

// ---------------- spectral mix via MFMA: block = (x-major, lvl); 256 thr = 4 waves.
__global__ __launch_bounds__(256) void mix_mfma_k(const float2* __restrict__ xf_all,
        const unsigned short* __restrict__ wbh, const unsigned short* __restrict__ wbl,
        unsigned* __restrict__ ofp) {
    __shared__ unsigned ax[32*260];   // 33.3 KB packed bf16 hi/lo X [b][k], XOR swizzled
    int x = 0;
    while (x < 64 && (int)blockIdx.x >= D_XP[x+1]) x++;
    int lvl = blockIdx.x - D_XP[x];
    int nh = 4096 >> lvl;
    const float2* xfL = xf_all + (size_t)lvl*262144;
    int tid = threadIdx.x;
    for (int q = tid; q < 4096; q += 256) {
        int b = q >> 7, z = (q >> 6) & 1, i = q & 63;
        float2 v = xfL[((size_t)b*2 + z)*4096 + (size_t)x*64 + i];
        int sw = ((b >> 3) & 7) << 2;
        int kR = z*128 + i;
        ax[b*260 + (kR ^ sw)] = packhl(v.x);
        ax[b*260 + ((kR + 64) ^ sw)] = packhl(v.y);
    }
    __syncthreads();
    int w4 = tid >> 6, lane = tid & 63;
    int col = lane & 15, khi = lane >> 4;
    int mt = w4 & 1, nt0 = (w4 >> 1) * 8;
    int arow = mt*16 + col;
    int asw = ((arow >> 3) & 7) << 2;
    const unsigned* ap = ax + arow*260;
    const unsigned short* WBH = wbh + (size_t)x*65536;
    const unsigned short* WBL = wbl + (size_t)x*65536;
    f4v acc[8];
    #pragma unroll
    for (int n = 0; n < 8; n++) acc[n] = (f4v){0.f,0.f,0.f,0.f};
    #pragma unroll
    for (int kt = 0; kt < 8; kt++) {
        int cb = kt*32 + khi*8;
        uint4 a0 = *(const uint4*)(ap + (cb ^ asw));
        uint4 a1 = *(const uint4*)(ap + ((cb + 4) ^ asw));
        s8v ah, al;
        const unsigned* pw = &a0.x;
        #pragma unroll
        for (int j = 0; j < 4; j++) {
            ah[j] = (short)(pw[j] & 0xFFFFu);
            al[j] = (short)(pw[j] >> 16);
        }
        pw = &a1.x;
        #pragma unroll
        for (int j = 0; j < 4; j++) {
            ah[4+j] = (short)(pw[j] & 0xFFFFu);
            al[4+j] = (short)(pw[j] >> 16);
        }
        #pragma unroll
        for (int n = 0; n < 8; n++) {
            int nt = nt0 + n;
            size_t fo = (((size_t)kt*16 + nt)*64 + lane)*8;
            s8v bh = *(const s8v*)(WBH + fo);
            s8v bl = *(const s8v*)(WBL + fo);
            acc[n] = __builtin_amdgcn_mfma_f32_16x16x32_bf16(ah, bh, acc[n], 0, 0, 0);
            acc[n] = __builtin_amdgcn_mfma_f32_16x16x32_bf16(ah, bl, acc[n], 0, 0, 0);
            acc[n] = __builtin_amdgcn_mfma_f32_16x16x32_bf16(al, bh, acc[n], 0, 0, 0);
        }
    }
    float wfac = (x == 0 || 2*x == nh) ? 1.f : 2.f;   // irfft doubling; DC/Nyquist not doubled
    float sc = wfac / (float)nh;
    int k0 = 2*x;
    #pragma unroll
    for (int n = 0; n < 8; n++) {
        int nn = nt0 + n;
        int pn = nn >> 2;              // 0:udRe 1:ud(-Im) 2:usRe 3:us(-Im)
        int o = (nn & 3)*16 + col;
        int z = pn >> 1;
        int kr = k0 + (pn & 1);
        #pragma unroll
        for (int r = 0; r < 4; r++) {
            int b = mt*16 + khi*4 + r;
            size_t base = (((size_t)lvl*32 + b)*2 + z)*8192 + (size_t)kr*64 + o;
            ofp[base] = packhl(sc * acc[n][r]);
        }
    }
}

// ---------------- inverse truncated DFT via MFMA, z-MERGED, packed-G staging.
__global__ __launch_bounds__(256) void fft_inv_mfma_k(
        const unsigned* __restrict__ ofp,
        const unsigned short* __restrict__ Th,  const unsigned short* __restrict__ Tl,
        float* __restrict__ outbuf) {
    __shared__ unsigned gp[2*64*132];   // [z][o][k] packed u32 (67.6 KB)
    int lvl = 0;
    while (lvl < 12 && (int)blockIdx.x >= D_TB[lvl+1]) lvl++;
    int g = blockIdx.x - D_TB[lvl];
    int nh = 4096 >> lvl;
    int tbase = g * 64;
    int b = blockIdx.y;
    int tid = threadIdx.x;
    const unsigned* Gp = ofp + (((size_t)lvl*32 + b)*2)*8192;
    #pragma unroll
    for (int q = 0; q < 16; q++) {
        int fi = tid + 256*q;          // 0..4095, uint4 granules
        int z = fi >> 11;
        int rem = fi & 2047;
        int k = rem >> 4, o4 = (rem & 15)*4;
        uint4 v = *(const uint4*)(Gp + (size_t)z*8192 + (size_t)k*64 + o4);
        const unsigned* pw = &v.x;
        #pragma unroll
        for (int i = 0; i < 4; i++)
            gp[z*8448 + (o4+i)*132 + k] = pw[i];
    }
    __syncthreads();
    int w = tid >> 6;
    int lane = tid & 63;
    int tb = tbase + w*16;
    if (tb >= nh) return;
    int trow = lane & 15, khi = lane >> 4;
    int tA = tb + trow; if (tA >= nh) tA = nh - 1;    // clamp (stores guarded)
    const unsigned short* THp = Th + d_tof(lvl) + (size_t)tA*128 + khi*8;
    const unsigned short* TLp = Tl + d_tof(lvl) + (size_t)tA*128 + khi*8;
    f4v acc[8];
    #pragma unroll
    for (int n = 0; n < 8; n++) acc[n] = (f4v){0.f,0.f,0.f,0.f};
    #pragma unroll
    for (int kk = 0; kk < 4; kk++) {
        s8v ah = *(const s8v*)(THp + kk*32);
        s8v al = *(const s8v*)(TLp + kk*32);
        #pragma unroll
        for (int n = 0; n < 8; n++) {
            int z = n >> 2;
            int off = z*8448 + ((n & 3)*16 + trow)*132 + kk*32 + khi*8;
            uint4 w0 = *(const uint4*)(gp + off);
            uint4 w1 = *(const uint4*)(gp + off + 4);
            s8v bh, bl;
            const unsigned* pw = &w0.x;
            #pragma unroll
            for (int j = 0; j < 4; j++) {
                bh[j] = (short)(pw[j] & 0xFFFFu);
                bl[j] = (short)(pw[j] >> 16);
            }
            pw = &w1.x;
            #pragma unroll
            for (int j = 0; j < 4; j++) {
                bh[4+j] = (short)(pw[j] & 0xFFFFu);
                bl[4+j] = (short)(pw[j] >> 16);
            }
            acc[n] = __builtin_amdgcn_mfma_f32_16x16x32_bf16(ah, bh, acc[n], 0, 0, 0);
            acc[n] = __builtin_amdgcn_mfma_f32_16x16x32_bf16(ah, bl, acc[n], 0, 0, 0);
            acc[n] = __builtin_amdgcn_mfma_f32_16x16x32_bf16(al, bh, acc[n], 0, 0, 0);
        }
    }
    float* U0 = outbuf + d_udo(lvl) + (size_t)b * nh * CKD;
    float* U1 = outbuf + d_uso(lvl) + (size_t)b * nh * CKD;
    int thi4 = khi * 4;
    #pragma unroll
    for (int n = 0; n < 8; n++) {
        float* U = (n >> 2) ? U1 : U0;
        int ocol = (n & 3)*16 + trow;
        #pragma unroll
        for (int r = 0; r < 4; r++) {
            int t = tb + thi4 + r;
            if (t < nh) U[(size_t)t*64 + ocol] = acc[n][r];
        }
    }
}

// ---------------- fused reconstruction levels 12..6; one block per b; x stays in LDS
__global__ __launch_bounds__(256) void recon_small_k(const float* __restrict__ xt0,
        const float* __restrict__ outbuf,
        const float* __restrict__ rce, const float* __restrict__ rco,
        float* __restrict__ rb0) {
    __shared__ float xA[128*64];   // 32 KB
    __shared__ float xB[64*64];    // 16 KB
    int b = blockIdx.x, tid = threadIdx.x;
    if (tid < 64) xB[tid] = xt0[(size_t)b*64 + tid];
    __syncthreads();
    for (int i = 12; i >= 6; i--) {
        int nh = 4096 >> i;
        const float* cur = ((i == 12) || !(i & 1)) ? xB : xA;
        float* nxt = (i & 1) ? xB : xA;
        const float* Us = outbuf + d_uso(i) + (size_t)b*nh*CKD;
        const float* Ud = outbuf + d_udo(i) + (size_t)b*nh*CKD;
        for (int q = tid; q < nh*8; q += 256) {
            int c = q & 7, t = q >> 3;
            size_t base = (size_t)t*CKD + c*KK;
            float xc[16];
            float4 a0 = ld4(cur+base), a1 = ld4(cur+base+4);
            float4 u0 = ld4(Us+base),  u1 = ld4(Us+base+4);
            float4 d0 = ld4(Ud+base),  d1 = ld4(Ud+base+4);
            xc[0]=a0.x+u0.x; xc[1]=a0.y+u0.y; xc[2]=a0.z+u0.z; xc[3]=a0.w+u0.w;
            xc[4]=a1.x+u1.x; xc[5]=a1.y+u1.y; xc[6]=a1.z+u1.z; xc[7]=a1.w+u1.w;
            xc[8]=d0.x;  xc[9]=d0.y;  xc[10]=d0.z; xc[11]=d0.w;
            xc[12]=d1.x; xc[13]=d1.y; xc[14]=d1.z; xc[15]=d1.w;
            float e[8], o2[8];
            #pragma unroll
            for (int m = 0; m < 8; m++) { e[m] = 0.f; o2[m] = 0.f; }
            #pragma unroll
            for (int j = 0; j < 16; j++) {
                float xv = xc[j];
                #pragma unroll
                for (int m = 0; m < 8; m++) {
                    e[m]  = fmaf(xv, rce[j*8+m], e[m]);
                    o2[m] = fmaf(xv, rco[j*8+m], o2[m]);
                }
            }
            if (i > 6) {
                float* pe = nxt + (size_t)(2*t)*CKD + c*KK;
                #pragma unroll
                for (int j = 0; j < 8; j++) { pe[j] = e[j]; pe[CKD + j] = o2[j]; }
            } else {
                float* pe = rb0 + ((size_t)b*128 + 2*t)*CKD + c*KK;
                *(float4*)(pe)      = make_float4(e[0],e[1],e[2],e[3]);
                *(float4*)(pe+4)    = make_float4(e[4],e[5],e[6],e[7]);
                *(float4*)(pe+64)   = make_float4(o2[0],o2[1],o2[2],o2[3]);
                *(float4*)(pe+68)   = make_float4(o2[4],o2[5],o2[6],o2[7]);
            }
        }
        __syncthreads();
    }
}

// ---------------- reconstruct one big level: (x+Us, Ud) @ rc_e / rc_o, interleave
__global__ __launch_bounds__(256) void recon_k(const float* __restrict__ xin,
        const float* __restrict__ us, const float* __restrict__ ud,
        const float* __restrict__ rce, const float* __restrict__ rco,
        float* __restrict__ xout, int nh) {
    int idx = blockIdx.x*256 + threadIdx.x;
    if (idx >= BB*nh*CC) return;
    int c = idx & 7;
    int t = (idx >> 3) % nh;
    int b = idx / (nh*CC);
    size_t base = ((size_t)b*nh + t)*CKD + c*KK;
    float xc[16];
    float4 a0 = ld4(xin+base), a1 = ld4(xin+base+4);
    float4 u0 = ld4(us+base),  u1 = ld4(us+base+4);
    float4 d0 = ld4(ud+base),  d1 = ld4(ud+base+4);
    xc[0]=a0.x+u0.x; xc[1]=a0.y+u0.y; xc[2]=a0.z+u0.z; xc[3]=a0.w+u0.w;
    xc[4]=a1.x+u1.x; xc[5]=a1.y+u1.y; xc[6]=a1.z+u1.z; xc[7]=a1.w+u1.w;
    xc[8]=d0.x;  xc[9]=d0.y;  xc[10]=d0.z; xc[11]=d0.w;
    xc[12]=d1.x; xc[13]=d1.y; xc[14]=d1.z; xc[15]=d1.w;
    float e[8], o2[8];
    #pragma unroll
    for (int m = 0; m < 8; m++) { e[m] = 0.f; o2[m] = 0.f; }
    #pragma unroll
    for (int j = 0; j < 16; j++) {
        float xv = xc[j];
        #pragma unroll
        for (int m = 0; m < 8; m++) {
            e[m]  = fmaf(xv, rce[j*8+m], e[m]);
            o2[m] = fmaf(xv, rco[j*8+m], o2[m]);
        }
    }
    size_t ob = ((size_t)b*2*nh + 2*t)*CKD + c*KK;
    *(float4*)(xout+ob)      = make_float4(e[0],e[1],e[2],e[3]);
    *(float4*)(xout+ob+4)    = make_float4(e[4],e[5],e[6],e[7]);
    *(float4*)(xout+ob+64)   = make_float4(o2[0],o2[1],o2[2],o2[3]);
    *(float4*)(xout+ob+68)   = make_float4(o2[4],o2[5],o2[6],o2[7]);
}

extern "C" void kernel_launch(void* const* d_in, const int* in_sizes, int n_in,
                              void* d_out, int out_size, void* d_ws, size_t ws_size,
                              hipStream_t stream) {
    const float* x   = (const float*)d_in[0];
    const float* wAr = (const float*)d_in[1];
    const float* wAi = (const float*)d_in[2];
    const float* wBr = (const float*)d_in[3];
    const float* wBi = (const float*)d_in[4];
    const float* wCr = (const float*)d_in[5];
    const float* wCi = (const float*)d_in[6];
    const float* T0w = (const float*)d_in[7];
    const float* T0b = (const float*)d_in[8];
    const float* ecs = (const float*)d_in[9];
    const float* ecd = (const float*)d_in[10];
    const float* rce = (const float*)d_in[11];
    const float* rco = (const float*)d_in[12];
    float* out = (float*)d_out;
    float* wsf = (float*)d_ws;

    // workspace layout (floats)
    size_t p = 0;
    float2* xf_all = (float2*)(wsf + p); p += 6815744;               // 27 MB
    unsigned* ofp = (unsigned*)(wsf + p); p += 6815744;              // 27 MB packed G (hi|lo)
    unsigned short* Th  = (unsigned short*)(wsf + p); p += 528384;   // 2.1 MB (inv trig hi)
    unsigned short* Tl  = (unsigned short*)(wsf + p); p += 528384;   // 2.1 MB
    unsigned short* Tfh = (unsigned short*)(wsf + p); p += 573440;   // 2.3 MB (fwd trig hi, frag-ordered)
    unsigned short* Tfl = (unsigned short*)(wsf + p); p += 573440;   // 2.3 MB
    float*  wt   = wsf + p; p += 1572864;                            // 6.3 MB transposed W
    unsigned short* wbh = (unsigned short*)(wsf + p); p += 2097152;  // 8.4 MB W_big hi (frag-ordered)
    unsigned short* wbl = (unsigned short*)(wsf + p); p += 2097152;  // 8.4 MB W_big lo
    float*  xt0  = wsf + p; p += 2048;
    float*  rb0  = wsf + p; p += 4194304;
    float*  rb1  = wsf + p; p += 8388608;
    unsigned* pv = (unsigned*)(wsf + p); p += 34078720;              // 136 MB packed V (frag-ordered)
    (void)ws_size; (void)in_sizes; (void)n_in; (void)out_size;

    size_t udo[13], uso[13];
    for (int i = 0; i < 13; i++) {
        udo[i] = 33554432ull - (16777216u >> i);
        uso[i] = 50329600ull - (16777216u >> i);
    }
    const int kbs_h[5] = {128,64,32,16,8};
    const int pvp_h[5] = {0,128,192,224,240};

    // tables (independent of data chain): trig, W transpose, big mixing matrix
    gen_tbl2_k<<<dim3(2048, 13, 2), 256, 0, stream>>>(Th, Tl, Tfh, Tfl);
    wtr_k<<<dim3(64, 6), 256, 0, stream>>>(wAr, wAi, wBr, wBi, wCr, wCi, wt);
    wbig_k<<<dim3(64, 32), 256, 0, stream>>>(wt, wbh, wbl);

    // decomposition: big levels 0..4 (emit s fp32 + packed pv), levels 5..12 + T0 fused
    for (int i = 0; i < 5; i++) {
        int nh = 4096 >> i;
        const float* xin_l = (i == 0) ? x : (out + uso[i-1]);
        decomp_k<<<dim3(nh/128, BB), 256, 0, stream>>>(xin_l, ecd, ecs,
                out + uso[i], pv + (size_t)pvp_h[i]*131072, nh, kbs_h[i]);
    }
    decomp_small_k<<<BB, 256, 0, stream>>>(out + uso[4], ecd, ecs, T0w, T0b, pv, xt0);

    // spectral pipeline: fwd(MFMA, full-K) -> mix(MFMA) -> inv(MFMA)
    fft_fwd_mfma_k<<<dim3(13, BB), 256, 0, stream>>>(pv, Tfh, Tfl, xf_all);
    mix_mfma_k<<<454, 256, 0, stream>>>(xf_all, wbh, wbl, ofp);
    fft_inv_mfma_k<<<dim3(133, BB), 256, 0, stream>>>(ofp, Th, Tl, out);

    // reconstruction: levels 12..6 fused (output -> rb0), then big levels 5..0
    recon_small_k<<<BB, 256, 0, stream>>>(xt0, out, rce, rco, rb0);
    const float* rin = rb0;
    for (int i = 5; i >= 0; i--) {
        int nh = 4096 >> i;
        float* ro = (i == 0) ? out : ((i & 1) ? rb1 : rb0);
        int tot = BB * nh * CC;
        recon_k<<<(tot + 255)/256, 256, 0, stream>>>(rin, out + uso[i], out + udo[i], rce, rco, ro, nh);
        rin = ro;
    }
}

// Round 16
// 496.880 us; speedup vs baseline: 1.2587x; 1.2587x over previous
//
#include <hip/hip_runtime.h>

#define BB 32
#define CKD 64
#define CC 8
#define KK 8
#define FPW 132   // u32 pitch for packed V-staging

// level tables (compile-time; N=8192, 13 levels)
__device__ const int D_KBS[13] = {128,64,32,16,8,4,2,1,1,1,1,1,1};            // 32-t kb count per level
__device__ const int D_PVP[13] = {0,128,192,224,240,248,252,254,255,256,257,258,259}; // pv kb prefix
__device__ const int D_FCB[14] = {0,8,12,14,15,16,17,18,19,20,21,22,23,24};   // fwd slot prefix (16-kb slots)
__device__ const int D_TB[14] = {0,64,96,112,120,124,126,127,128,129,130,131,132,133}; // inv 64-t tile prefix
__device__ const int D_FTOF[13] = {0,524288,786432,917504,983040,1015808,1032192,
                                   1048576,1064960,1081344,1097728,1114112,1130496}; // fwd table elem offsets
// mix x-major prefix
__device__ const int D_XP[65] = {0,13,25,36,46,56,65,74,83,92,100,108,116,124,132,140,
    148,156,163,170,177,184,191,198,205,212,219,226,233,240,247,254,261,268,274,280,
    286,292,298,304,310,316,322,328,334,340,346,352,358,364,370,376,382,388,394,400,
    406,412,418,424,430,436,442,448,454};

typedef __attribute__((ext_vector_type(4))) short s4v;
typedef __attribute__((ext_vector_type(8))) short s8v;
typedef __attribute__((ext_vector_type(4))) float f4v;

static __device__ __forceinline__ float4 ld4(const float* p){ return *(const float4*)p; }
static __device__ __forceinline__ size_t d_udo(int i){ return 33554432ull - (16777216u >> i); }
static __device__ __forceinline__ size_t d_uso(int i){ return 50329600ull - (16777216u >> i); }
static __device__ __forceinline__ size_t d_tof(int i){ return 128ull * (8192u - (8192u >> i)); }

static __device__ __forceinline__ unsigned short b16(float f) {
    unsigned u = __float_as_uint(f);
    u += 0x7FFFu + ((u >> 16) & 1u);      // RNE
    return (unsigned short)(u >> 16);
}
static __device__ __forceinline__ float fb16(unsigned short h) {
    return __uint_as_float(((unsigned)h) << 16);
}
static __device__ __forceinline__ unsigned packhl(float f) {
    unsigned u = __float_as_uint(f);
    unsigned hi = u & 0xFFFF0000u;        // truncation split
    float r = f - __uint_as_float(hi);
    unsigned lo = __float_as_uint(r) & 0xFFFF0000u;
    return (hi >> 16) | lo;
}

// ---------------- combined trig-table generation (z=0: inv T, z=1: fwd F frag-ordered)
__global__ __launch_bounds__(256) void gen_tbl2_k(unsigned short* __restrict__ Th,
        unsigned short* __restrict__ Tl, unsigned short* __restrict__ Tfh,
        unsigned short* __restrict__ Tfl) {
    int lvl = blockIdx.y;
    int nh = 4096 >> lvl;
    int idx = blockIdx.x * 256 + threadIdx.x;
    if (blockIdx.z == 0) {
        if (idx >= nh * 128) return;
        int t = idx >> 7, k = idx & 127, x = k >> 1;
        int l = nh / 2 + 1; if (l > 64) l = 64;
        float v = 0.f;
        if (x < l) {
            int r = (x * t) & (nh - 1);
            float th = 6.283185307179586f * ((float)r / (float)nh);
            float s, c; sincosf(th, &s, &c);
            v = (k & 1) ? s : c;
        }
        unsigned short hi = b16(v);
        unsigned short lo = b16(v - fb16(hi));
        size_t off = d_tof(lvl) + idx;
        Th[off] = hi; Tl[off] = lo;
    } else {
        int nhp = nh < 128 ? 128 : nh;
        if (idx >= 128 * nhp) return;
        int j = idx & 7;
        int lane = (idx >> 3) & 63;
        int mt = (idx >> 9) & 7;
        int kb = idx >> 12;
        int row = mt*16 + (lane & 15);
        int t = kb*32 + (lane >> 4)*8 + j;
        int x = row >> 1;
        int l = nh / 2 + 1; if (l > 64) l = 64;
        float v = 0.f;
        if (x < l && t < nh) {
            int r = (x * t) & (nh - 1);
            float th = 6.283185307179586f * ((float)r / (float)nh);
            float s, c; sincosf(th, &s, &c);
            v = (row & 1) ? -s : c;
        }
        unsigned short hi = b16(v);
        unsigned short lo = b16(v - fb16(hi));
        size_t off = (size_t)D_FTOF[lvl] + idx;
        Tfh[off] = hi; Tfl[off] = lo;
    }
}

// ---------------- W transpose: wt[arr][x][i*64+o] = W_arr[(i*64+o)*64 + x]
__global__ __launch_bounds__(256) void wtr_k(const float* __restrict__ wAr,
        const float* __restrict__ wAi, const float* __restrict__ wBr,
        const float* __restrict__ wBi, const float* __restrict__ wCr,
        const float* __restrict__ wCi, float* __restrict__ wt) {
    int x = blockIdx.x, arr = blockIdx.y;
    const float* W;
    switch (arr) {
        case 0: W = wAr; break;
        case 1: W = wAi; break;
        case 2: W = wBr; break;
        case 3: W = wBi; break;
        case 4: W = wCr; break;
        default: W = wCi; break;
    }
    float* o = wt + ((size_t)arr*64 + x)*4096;
    for (int q = threadIdx.x; q < 4096; q += 256)
        o[q] = W[(size_t)q*64 + x];
}

// ---------------- big mixing matrix, FRAGMENT-ORDERED bf16 hi/lo, signs/zeros folded.
__global__ __launch_bounds__(256) void wbig_k(const float* __restrict__ wt,
        unsigned short* __restrict__ wbh, unsigned short* __restrict__ wbl) {
    int x = blockIdx.x;
    int f0 = blockIdx.y * 2048;
    for (int q = threadIdx.x; q < 2048; q += 256) {
        int f = f0 + q;
        int j = f & 7;
        int lane = (f >> 3) & 63;
        int nt = (f >> 9) & 15;
        int kt = f >> 13;
        int k = kt*32 + (lane >> 4)*8 + j;
        int n = nt*16 + (lane & 15);
        int pk = k >> 6, i = k & 63;
        int pn = n >> 6, o = n & 63;
        int arr; float sgn;
        switch ((pn << 2) | pk) {
            case 0:  arr = 0; sgn =  1.f; break;
            case 1:  arr = 1; sgn = -1.f; break;
            case 2:  arr = 2; sgn =  1.f; break;
            case 3:  arr = 3; sgn = -1.f; break;
            case 4:  arr = 1; sgn = -1.f; break;
            case 5:  arr = 0; sgn = -1.f; break;
            case 6:  arr = 3; sgn = -1.f; break;
            case 7:  arr = 2; sgn = -1.f; break;
            case 8:  arr = 4; sgn =  1.f; break;
            case 9:  arr = 5; sgn = -1.f; break;
            case 12: arr = 5; sgn = -1.f; break;
            case 13: arr = 4; sgn = -1.f; break;
            default: arr = -1; sgn = 0.f; break;
        }
        float v = 0.f;
        if (arr >= 0) v = sgn * wt[((size_t)arr*64 + x)*4096 + (size_t)i*64 + o];
        unsigned short h = b16(v);
        unsigned short l2 = b16(v - fb16(h));
        wbh[(size_t)x*65536 + f] = h;
        wbl[(size_t)x*65536 + f] = l2;
    }
}

// ---------------- decompose (big levels 0..4): writes s fp32 (chain) + packed frag pv (d,s).
__global__ __launch_bounds__(256) void decomp_k(const float* __restrict__ xin,
        const float* __restrict__ ecd, const float* __restrict__ ecs,
        float* __restrict__ sslot, unsigned* __restrict__ pvL,
        int nh, int kbs) {
    __shared__ unsigned vd[64*FPW];   // packed d [i][t] swizzled (33.8 KB)
    __shared__ unsigned vs[64*FPW];   // packed s
    int chunk = blockIdx.x, b = blockIdx.y;
    int t0 = chunk * 128;
    int tid = threadIdx.x;
    #pragma unroll
    for (int wi = 0; wi < 4; wi++) {
        int q = tid + wi*256;            // 1024 = 128 t x 8 c
        int c = q & 7, tl = q >> 3;
        int t = t0 + tl;
        const float* p0 = xin + ((size_t)b*2*nh + 2*t)*CKD + c*KK;
        float xa[16];
        float4 v;
        v = ld4(p0);      xa[0]=v.x; xa[1]=v.y; xa[2]=v.z; xa[3]=v.w;
        v = ld4(p0+4);    xa[4]=v.x; xa[5]=v.y; xa[6]=v.z; xa[7]=v.w;
        v = ld4(p0+64);   xa[8]=v.x; xa[9]=v.y; xa[10]=v.z; xa[11]=v.w;
        v = ld4(p0+68);   xa[12]=v.x; xa[13]=v.y; xa[14]=v.z; xa[15]=v.w;
        float dd[8], ss[8];
        #pragma unroll
        for (int m = 0; m < 8; m++) { dd[m] = 0.f; ss[m] = 0.f; }
        #pragma unroll
        for (int j = 0; j < 16; j++) {
            float xv = xa[j];
            #pragma unroll
            for (int m = 0; m < 8; m++) {
                dd[m] = fmaf(xv, ecd[j*8+m], dd[m]);
                ss[m] = fmaf(xv, ecs[j*8+m], ss[m]);
            }
        }
        float* sp = sslot + ((size_t)b*nh + t)*CKD + c*KK;
        *(float4*)sp     = make_float4(ss[0],ss[1],ss[2],ss[3]);
        *(float4*)(sp+4) = make_float4(ss[4],ss[5],ss[6],ss[7]);
        #pragma unroll
        for (int j = 0; j < 8; j++) {
            int row = c*8 + j;
            int cw = tl ^ (((row >> 3) & 7) << 2);
            vd[row*FPW + cw] = packhl(dd[j]);
            vs[row*FPW + cw] = packhl(ss[j]);
        }
    }
    __syncthreads();
    unsigned* P = pvL + (size_t)b*kbs*4096;
    #pragma unroll
    for (int qq = 0; qq < 16; qq++) {
        int fi = tid + 256*qq;           // 4096 uint4 granules = 2 z x 2048
        int z = fi >> 11;
        int rem = fi & 2047;
        int j4 = rem & 1;
        int lane2 = (rem >> 1) & 63;
        int nt = (rem >> 7) & 3;
        int kbl = rem >> 9;
        int kbg = chunk*4 + kbl;
        int lrow = nt*16 + (lane2 & 15);
        int cb = kbl*32 + (lane2 >> 4)*8 + j4*4;
        int rsw = ((lrow >> 3) & 7) << 2;
        const unsigned* src = z ? vs : vd;
        uint4 v = *(const uint4*)&src[lrow*FPW + (cb ^ rsw)];
        *(uint4*)(P + (((size_t)(kbg*8 + z*4 + nt))*64 + lane2)*8 + j4*4) = v;
    }
}

// ---------------- fused decompose levels 5..12 (+T0): all in LDS; emits packed frag pv only.
__global__ __launch_bounds__(256) void decomp_small_k(const float* __restrict__ s4base,
        const float* __restrict__ ecd, const float* __restrict__ ecs,
        const float* __restrict__ T0w, const float* __restrict__ T0b,
        unsigned* __restrict__ pv, float* __restrict__ xt0) {
    __shared__ float sA[128*64];      // 32 KB
    __shared__ float sB[64*64];       // 16 KB
    __shared__ unsigned sDp[128*64];  // 32 KB packed d [t][i]
    int b = blockIdx.x, tid = threadIdx.x;
    for (int lvl = 5; lvl <= 12; lvl++) {
        int nh = 4096 >> lvl;
        const float* src = (lvl == 5) ? (s4base + (size_t)b*256*CKD)
                                      : (((lvl - 6) & 1) ? sB : sA);
        float* dst = ((lvl - 5) & 1) ? sB : sA;
        for (int q = tid; q < nh*8; q += 256) {
            int c = q & 7, t = q >> 3;
            const float* p0 = src + (size_t)(2*t)*CKD + c*KK;
            float xa[16];
            float4 v;
            v = ld4(p0);      xa[0]=v.x; xa[1]=v.y; xa[2]=v.z; xa[3]=v.w;
            v = ld4(p0+4);    xa[4]=v.x; xa[5]=v.y; xa[6]=v.z; xa[7]=v.w;
            v = ld4(p0+64);   xa[8]=v.x; xa[9]=v.y; xa[10]=v.z; xa[11]=v.w;
            v = ld4(p0+68);   xa[12]=v.x; xa[13]=v.y; xa[14]=v.z; xa[15]=v.w;
            float dd[8], ss[8];
            #pragma unroll
            for (int m = 0; m < 8; m++) { dd[m] = 0.f; ss[m] = 0.f; }
            #pragma unroll
            for (int j = 0; j < 16; j++) {
                float xv = xa[j];
                #pragma unroll
                for (int m = 0; m < 8; m++) {
                    dd[m] = fmaf(xv, ecd[j*8+m], dd[m]);
                    ss[m] = fmaf(xv, ecs[j*8+m], ss[m]);
                }
            }
            float* dl = dst + t*CKD + c*KK;
            unsigned* dp = sDp + t*CKD + c*KK;
            #pragma unroll
            for (int j = 0; j < 8; j++) {
                dl[j] = ss[j];
                dp[j] = packhl(dd[j]);
            }
        }
        __syncthreads();
        // fragment store to pv (d from sDp, s packed from dst)
        int kbs = D_KBS[lvl];
        unsigned* P = pv + (size_t)D_PVP[lvl]*131072 + (size_t)b*kbs*4096;
        for (int f = tid; f < kbs*512; f += 256) {
            int lane = f & 63;
            int zn = (f >> 6) & 7;
            int kb = f >> 9;
            int z = zn >> 2, nt = zn & 3;
            int i = nt*16 + (lane & 15);
            int tb2 = kb*32 + (lane >> 4)*8;
            unsigned vals[8];
            #pragma unroll
            for (int j = 0; j < 8; j++) {
                int t = tb2 + j;
                vals[j] = z ? packhl(dst[t*CKD + i]) : sDp[t*CKD + i];
            }
            unsigned* pp = P + (((size_t)(kb*8 + z*4 + nt))*64 + lane)*8;
            *(uint4*)pp     = make_uint4(vals[0],vals[1],vals[2],vals[3]);
            *(uint4*)(pp+4) = make_uint4(vals[4],vals[5],vals[6],vals[7]);
        }
        __syncthreads();
    }
    // T0 linear on s12 (row 0 of sB)
    if (tid < 64) {
        int m = tid & 7, c = tid >> 3;
        const float* xr = sB + c*KK;
        float a = T0b[m];
        #pragma unroll
        for (int j = 0; j < 8; j++) a = fmaf(xr[j], T0w[m*8+j], a);
        xt0[(size_t)b*64 + tid] = a;
    }
}

// ---------------- forward truncated DFT via MFMA, LDS-FREE, split-K (16 kb/slot).
// grid (24 slots, 32 b); partials for multi-slot lvls (0..2), direct xf_all otherwise.
__global__ __launch_bounds__(256) void fft_fwd_mfma_k(const unsigned* __restrict__ pv,
        const unsigned short* __restrict__ Tfh, const unsigned short* __restrict__ Tfl,
        float* __restrict__ xfpf, float2* __restrict__ xf_all) {
    int slot = blockIdx.x;
    int lvl = 0;
    while (lvl < 12 && slot >= D_FCB[lvl+1]) lvl++;
    int kbs = D_KBS[lvl];
    int nslots = D_FCB[lvl+1] - D_FCB[lvl];
    int kb0 = (slot - D_FCB[lvl]) * 16;
    int kb1 = kb0 + 16; if (kb1 > kbs) kb1 = kbs;
    int b = blockIdx.y;
    const unsigned* PV = pv + (size_t)D_PVP[lvl]*131072 + (size_t)b*kbs*4096;
    const unsigned short* THb = Tfh + D_FTOF[lvl];
    const unsigned short* TLb = Tfl + D_FTOF[lvl];
    int tid = threadIdx.x;
    int w = tid >> 6, lane = tid & 63;
    int col = lane & 15, khi = lane >> 4;
    int mt0 = w * 2;                        // wave handles m-tiles {2w, 2w+1}
    f4v acc[2][8];
    #pragma unroll
    for (int m = 0; m < 2; m++)
        #pragma unroll
        for (int n = 0; n < 8; n++) acc[m][n] = (f4v){0.f,0.f,0.f,0.f};
    for (int kb = kb0; kb < kb1; kb++) {
        s8v ah[2], al[2];
        #pragma unroll
        for (int m = 0; m < 2; m++) {
            size_t fo = (((size_t)kb*8 + (mt0 + m))*64 + lane)*8;   // lane-contiguous
            ah[m] = *(const s8v*)(THb + fo);
            al[m] = *(const s8v*)(TLb + fo);
        }
        #pragma unroll
        for (int n = 0; n < 8; n++) {
            const unsigned* bp = PV + (((size_t)(kb*8 + n))*64 + lane)*8;
            uint4 w0 = *(const uint4*)bp;
            uint4 w1 = *(const uint4*)(bp + 4);
            s8v bh, bl;
            const unsigned* pw = &w0.x;
            #pragma unroll
            for (int j = 0; j < 4; j++) {
                bh[j] = (short)(pw[j] & 0xFFFFu);
                bl[j] = (short)(pw[j] >> 16);
            }
            pw = &w1.x;
            #pragma unroll
            for (int j = 0; j < 4; j++) {
                bh[4+j] = (short)(pw[j] & 0xFFFFu);
                bl[4+j] = (short)(pw[j] >> 16);
            }
            #pragma unroll
            for (int m = 0; m < 2; m++) {
                acc[m][n] = __builtin_amdgcn_mfma_f32_16x16x32_bf16(ah[m], bh, acc[m][n], 0,0,0);
                acc[m][n] = __builtin_amdgcn_mfma_f32_16x16x32_bf16(ah[m], bl, acc[m][n], 0,0,0);
                acc[m][n] = __builtin_amdgcn_mfma_f32_16x16x32_bf16(al[m], bh, acc[m][n], 0,0,0);
            }
        }
    }
    if (nslots == 1) {
        float* XB = (float*)xf_all + (size_t)lvl*524288 + (size_t)b*16384;
        #pragma unroll
        for (int m = 0; m < 2; m++) {
            int m0 = (mt0 + m)*16 + khi*4;
            #pragma unroll
            for (int n = 0; n < 8; n++) {
                int ic = n*16 + col;
                int z = ic >> 6, i = ic & 63;
                float* X = XB + (size_t)z*8192;
                #pragma unroll
                for (int r = 0; r < 4; r++) {
                    int row = m0 + r;
                    X[(((size_t)(row >> 1)*64 + i) << 1) | (row & 1)] = acc[m][n][r];
                }
            }
        }
    } else {
        #pragma unroll
        for (int m = 0; m < 2; m++) {
            int m0 = (mt0 + m)*16 + khi*4;
            #pragma unroll
            for (int n = 0; n < 8; n++) {
                int ic = n*16 + col;
                int z = ic >> 6, i = ic & 63;
                float* P = xfpf + ((size_t)slot*64 + (size_t)b*2 + z) * 8192;
                #pragma unroll
                for (int r = 0; r < 4; r++)
                    P[(size_t)(m0 + r)*64 + i] = acc[m][n][r];
            }
        }
    }
}

// ---------------- sum fwd partials (levels 0..2), relayout -> xf_all float2
__global__ __launch_bounds__(256) void reduce_fwd_k(const float* __restrict__ xfpf,
        float2* __restrict__ xf_all) {
    int lvl = blockIdx.y;
    int e = blockIdx.x * 256 + threadIdx.x;   // < 64*4096
    int j = e & 4095;
    int bz = e >> 12;
    int x = j >> 6, i = j & 63;
    int c0 = D_FCB[lvl], c1 = D_FCB[lvl+1];
    float re = 0.f, im = 0.f;
    for (int c = c0; c < c1; c++) {
        size_t base = ((size_t)c*64 + bz) * 8192;
        re += xfpf[base + (size_t)(2*x)*64 + i];
        im += xfpf[base + (size_t)(2*x+1)*64 + i];
    }
    xf_all[(size_t)lvl*262144 + (size_t)bz*4096 + j] = make_float2(re, im);
}

// ---------------- spectral mix via MFMA: block = (x-major, lvl); 256 thr = 4 waves.
__global__ __launch_bounds__(256) void mix_mfma_k(const float2* __restrict__ xf_all,
        const unsigned short* __restrict__ wbh, const unsigned short* __restrict__ wbl,
        unsigned* __restrict__ ofp) {
    __shared__ unsigned ax[32*260];   // 33.3 KB packed bf16 hi/lo X [b][k], XOR swizzled
    int x = 0;
    while (x < 64 && (int)blockIdx.x >= D_XP[x+1]) x++;
    int lvl = blockIdx.x - D_XP[x];
    int nh = 4096 >> lvl;
    const float2* xfL = xf_all + (size_t)lvl*262144;
    int tid = threadIdx.x;
    for (int q = tid; q < 4096; q += 256) {
        int b = q >> 7, z = (q >> 6) & 1, i = q & 63;
        float2 v = xfL[((size_t)b*2 + z)*4096 + (size_t)x*64 + i];
        int sw = ((b >> 3) & 7) << 2;
        int kR = z*128 + i;
        ax[b*260 + (kR ^ sw)] = packhl(v.x);
        ax[b*260 + ((kR + 64) ^ sw)] = packhl(v.y);
    }
    __syncthreads();
    int w4 = tid >> 6, lane = tid & 63;
    int col = lane & 15, khi = lane >> 4;
    int mt = w4 & 1, nt0 = (w4 >> 1) * 8;
    int arow = mt*16 + col;
    int asw = ((arow >> 3) & 7) << 2;
    const unsigned* ap = ax + arow*260;
    const unsigned short* WBH = wbh + (size_t)x*65536;
    const unsigned short* WBL = wbl + (size_t)x*65536;
    f4v acc[8];
    #pragma unroll
    for (int n = 0; n < 8; n++) acc[n] = (f4v){0.f,0.f,0.f,0.f};
    #pragma unroll
    for (int kt = 0; kt < 8; kt++) {
        int cb = kt*32 + khi*8;
        uint4 a0 = *(const uint4*)(ap + (cb ^ asw));
        uint4 a1 = *(const uint4*)(ap + ((cb + 4) ^ asw));
        s8v ah, al;
        const unsigned* pw = &a0.x;
        #pragma unroll
        for (int j = 0; j < 4; j++) {
            ah[j] = (short)(pw[j] & 0xFFFFu);
            al[j] = (short)(pw[j] >> 16);
        }
        pw = &a1.x;
        #pragma unroll
        for (int j = 0; j < 4; j++) {
            ah[4+j] = (short)(pw[j] & 0xFFFFu);
            al[4+j] = (short)(pw[j] >> 16);
        }
        #pragma unroll
        for (int n = 0; n < 8; n++) {
            int nt = nt0 + n;
            size_t fo = (((size_t)kt*16 + nt)*64 + lane)*8;
            s8v bh = *(const s8v*)(WBH + fo);
            s8v bl = *(const s8v*)(WBL + fo);
            acc[n] = __builtin_amdgcn_mfma_f32_16x16x32_bf16(ah, bh, acc[n], 0, 0, 0);
            acc[n] = __builtin_amdgcn_mfma_f32_16x16x32_bf16(ah, bl, acc[n], 0, 0, 0);
            acc[n] = __builtin_amdgcn_mfma_f32_16x16x32_bf16(al, bh, acc[n], 0, 0, 0);
        }
    }
    float wfac = (x == 0 || 2*x == nh) ? 1.f : 2.f;   // irfft doubling; DC/Nyquist not doubled
    float sc = wfac / (float)nh;
    int k0 = 2*x;
    #pragma unroll
    for (int n = 0; n < 8; n++) {
        int nn = nt0 + n;
        int pn = nn >> 2;              // 0:udRe 1:ud(-Im) 2:usRe 3:us(-Im)
        int o = (nn & 3)*16 + col;
        int z = pn >> 1;
        int kr = k0 + (pn & 1);
        #pragma unroll
        for (int r = 0; r < 4; r++) {
            int b = mt*16 + khi*4 + r;
            size_t base = (((size_t)lvl*32 + b)*2 + z)*8192 + (size_t)kr*64 + o;
            ofp[base] = packhl(sc * acc[n][r]);
        }
    }
}

// ---------------- inverse truncated DFT via MFMA, z-MERGED, packed-G staging.
__global__ __launch_bounds__(256) void fft_inv_mfma_k(
        const unsigned* __restrict__ ofp,
        const unsigned short* __restrict__ Th,  const unsigned short* __restrict__ Tl,
        float* __restrict__ outbuf) {
    __shared__ unsigned gp[2*64*132];   // [z][o][k] packed u32 (67.6 KB)
    int lvl = 0;
    while (lvl < 12 && (int)blockIdx.x >= D_TB[lvl+1]) lvl++;
    int g = blockIdx.x - D_TB[lvl];
    int nh = 4096 >> lvl;
    int tbase = g * 64;
    int b = blockIdx.y;
    int tid = threadIdx.x;
    const unsigned* Gp = ofp + (((size_t)lvl*32 + b)*2)*8192;
    #pragma unroll
    for (int q = 0; q < 16; q++) {
        int fi = tid + 256*q;          // 0..4095, uint4 granules
        int z = fi >> 11;
        int rem = fi & 2047;
        int k = rem >> 4, o4 = (rem & 15)*4;
        uint4 v = *(const uint4*)(Gp + (size_t)z*8192 + (size_t)k*64 + o4);
        const unsigned* pw = &v.x;
        #pragma unroll
        for (int i = 0; i < 4; i++)
            gp[z*8448 + (o4+i)*132 + k] = pw[i];
    }
    __syncthreads();
    int w = tid >> 6;
    int lane = tid & 63;
    int tb = tbase + w*16;
    if (tb >= nh) return;
    int trow = lane & 15, khi = lane >> 4;
    int tA = tb + trow; if (tA >= nh) tA = nh - 1;    // clamp (stores guarded)
    const unsigned short* THp = Th + d_tof(lvl) + (size_t)tA*128 + khi*8;
    const unsigned short* TLp = Tl + d_tof(lvl) + (size_t)tA*128 + khi*8;
    f4v acc[8];
    #pragma unroll
    for (int n = 0; n < 8; n++) acc[n] = (f4v){0.f,0.f,0.f,0.f};
    #pragma unroll
    for (int kk = 0; kk < 4; kk++) {
        s8v ah = *(const s8v*)(THp + kk*32);
        s8v al = *(const s8v*)(TLp + kk*32);
        #pragma unroll
        for (int n = 0; n < 8; n++) {
            int z = n >> 2;
            int off = z*8448 + ((n & 3)*16 + trow)*132 + kk*32 + khi*8;
            uint4 w0 = *(const uint4*)(gp + off);
            uint4 w1 = *(const uint4*)(gp + off + 4);
            s8v bh, bl;
            const unsigned* pw = &w0.x;
            #pragma unroll
            for (int j = 0; j < 4; j++) {
                bh[j] = (short)(pw[j] & 0xFFFFu);
                bl[j] = (short)(pw[j] >> 16);
            }
            pw = &w1.x;
            #pragma unroll
            for (int j = 0; j < 4; j++) {
                bh[4+j] = (short)(pw[j] & 0xFFFFu);
                bl[4+j] = (short)(pw[j] >> 16);
            }
            acc[n] = __builtin_amdgcn_mfma_f32_16x16x32_bf16(ah, bh, acc[n], 0, 0, 0);
            acc[n] = __builtin_amdgcn_mfma_f32_16x16x32_bf16(ah, bl, acc[n], 0, 0, 0);
            acc[n] = __builtin_amdgcn_mfma_f32_16x16x32_bf16(al, bh, acc[n], 0, 0, 0);
        }
    }
    float* U0 = outbuf + d_udo(lvl) + (size_t)b * nh * CKD;
    float* U1 = outbuf + d_uso(lvl) + (size_t)b * nh * CKD;
    int thi4 = khi * 4;
    #pragma unroll
    for (int n = 0; n < 8; n++) {
        float* U = (n >> 2) ? U1 : U0;
        int ocol = (n & 3)*16 + trow;
        #pragma unroll
        for (int r = 0; r < 4; r++) {
            int t = tb + thi4 + r;
            if (t < nh) U[(size_t)t*64 + ocol] = acc[n][r];
        }
    }
}

// ---------------- fused reconstruction levels 12..6; one block per b; x stays in LDS
__global__ __launch_bounds__(256) void recon_small_k(const float* __restrict__ xt0,
        const float* __restrict__ outbuf,
        const float* __restrict__ rce, const float* __restrict__ rco,
        float* __restrict__ rb0) {
    __shared__ float xA[128*64];   // 32 KB
    __shared__ float xB[64*64];    // 16 KB
    int b = blockIdx.x, tid = threadIdx.x;
    if (tid < 64) xB[tid] = xt0[(size_t)b*64 + tid];
    __syncthreads();
    for (int i = 12; i >= 6; i--) {
        int nh = 4096 >> i;
        const float* cur = ((i == 12) || !(i & 1)) ? xB : xA;
        float* nxt = (i & 1) ? xB : xA;
        const float* Us = outbuf + d_uso(i) + (size_t)b*nh*CKD;
        const float* Ud = outbuf + d_udo(i) + (size_t)b*nh*CKD;
        for (int q = tid; q < nh*8; q += 256) {
            int c = q & 7, t = q >> 3;
            size_t base = (size_t)t*CKD + c*KK;
            float xc[16];
            float4 a0 = ld4(cur+base), a1 = ld4(cur+base+4);
            float4 u0 = ld4(Us+base),  u1 = ld4(Us+base+4);
            float4 d0 = ld4(Ud+base),  d1 = ld4(Ud+base+4);
            xc[0]=a0.x+u0.x; xc[1]=a0.y+u0.y; xc[2]=a0.z+u0.z; xc[3]=a0.w+u0.w;
            xc[4]=a1.x+u1.x; xc[5]=a1.y+u1.y; xc[6]=a1.z+u1.z; xc[7]=a1.w+u1.w;
            xc[8]=d0.x;  xc[9]=d0.y;  xc[10]=d0.z; xc[11]=d0.w;
            xc[12]=d1.x; xc[13]=d1.y; xc[14]=d1.z; xc[15]=d1.w;
            float e[8], o2[8];
            #pragma unroll
            for (int m = 0; m < 8; m++) { e[m] = 0.f; o2[m] = 0.f; }
            #pragma unroll
            for (int j = 0; j < 16; j++) {
                float xv = xc[j];
                #pragma unroll
                for (int m = 0; m < 8; m++) {
                    e[m]  = fmaf(xv, rce[j*8+m], e[m]);
                    o2[m] = fmaf(xv, rco[j*8+m], o2[m]);
                }
            }
            if (i > 6) {
                float* pe = nxt + (size_t)(2*t)*CKD + c*KK;
                #pragma unroll
                for (int j = 0; j < 8; j++) { pe[j] = e[j]; pe[CKD + j] = o2[j]; }
            } else {
                float* pe = rb0 + ((size_t)b*128 + 2*t)*CKD + c*KK;
                *(float4*)(pe)      = make_float4(e[0],e[1],e[2],e[3]);
                *(float4*)(pe+4)    = make_float4(e[4],e[5],e[6],e[7]);
                *(float4*)(pe+64)   = make_float4(o2[0],o2[1],o2[2],o2[3]);
                *(float4*)(pe+68)   = make_float4(o2[4],o2[5],o2[6],o2[7]);
            }
        }
        __syncthreads();
    }
}

// ---------------- reconstruct one big level: (x+Us, Ud) @ rc_e / rc_o, interleave
__global__ __launch_bounds__(256) void recon_k(const float* __restrict__ xin,
        const float* __restrict__ us, const float* __restrict__ ud,
        const float* __restrict__ rce, const float* __restrict__ rco,
        float* __restrict__ xout, int nh) {
    int idx = blockIdx.x*256 + threadIdx.x;
    if (idx >= BB*nh*CC) return;
    int c = idx & 7;
    int t = (idx >> 3) % nh;
    int b = idx / (nh*CC);
    size_t base = ((size_t)b*nh + t)*CKD + c*KK;
    float xc[16];
    float4 a0 = ld4(xin+base), a1 = ld4(xin+base+4);
    float4 u0 = ld4(us+base),  u1 = ld4(us+base+4);
    float4 d0 = ld4(ud+base),  d1 = ld4(ud+base+4);
    xc[0]=a0.x+u0.x; xc[1]=a0.y+u0.y; xc[2]=a0.z+u0.z; xc[3]=a0.w+u0.w;
    xc[4]=a1.x+u1.x; xc[5]=a1.y+u1.y; xc[6]=a1.z+u1.z; xc[7]=a1.w+u1.w;
    xc[8]=d0.x;  xc[9]=d0.y;  xc[10]=d0.z; xc[11]=d0.w;
    xc[12]=d1.x; xc[13]=d1.y; xc[14]=d1.z; xc[15]=d1.w;
    float e[8], o2[8];
    #pragma unroll
    for (int m = 0; m < 8; m++) { e[m] = 0.f; o2[m] = 0.f; }
    #pragma unroll
    for (int j = 0; j < 16; j++) {
        float xv = xc[j];
        #pragma unroll
        for (int m = 0; m < 8; m++) {
            e[m]  = fmaf(xv, rce[j*8+m], e[m]);
            o2[m] = fmaf(xv, rco[j*8+m], o2[m]);
        }
    }
    size_t ob = ((size_t)b*2*nh + 2*t)*CKD + c*KK;
    *(float4*)(xout+ob)      = make_float4(e[0],e[1],e[2],e[3]);
    *(float4*)(xout+ob+4)    = make_float4(e[4],e[5],e[6],e[7]);
    *(float4*)(xout+ob+64)   = make_float4(o2[0],o2[1],o2[2],o2[3]);
    *(float4*)(xout+ob+68)   = make_float4(o2[4],o2[5],o2[6],o2[7]);
}

extern "C" void kernel_launch(void* const* d_in, const int* in_sizes, int n_in,
                              void* d_out, int out_size, void* d_ws, size_t ws_size,
                              hipStream_t stream) {
    const float* x   = (const float*)d_in[0];
    const float* wAr = (const float*)d_in[1];
    const float* wAi = (const float*)d_in[2];
    const float* wBr = (const float*)d_in[3];
    const float* wBi = (const float*)d_in[4];
    const float* wCr = (const float*)d_in[5];
    const float* wCi = (const float*)d_in[6];
    const float* T0w = (const float*)d_in[7];
    const float* T0b = (const float*)d_in[8];
    const float* ecs = (const float*)d_in[9];
    const float* ecd = (const float*)d_in[10];
    const float* rce = (const float*)d_in[11];
    const float* rco = (const float*)d_in[12];
    float* out = (float*)d_out;
    float* wsf = (float*)d_ws;

    // workspace layout (floats)
    size_t p = 0;
    float2* xf_all = (float2*)(wsf + p); p += 6815744;               // 27 MB
    unsigned* ofp = (unsigned*)(wsf + p); p += 6815744;              // 27 MB packed G (hi|lo)
    unsigned short* Th  = (unsigned short*)(wsf + p); p += 528384;   // 2.1 MB (inv trig hi)
    unsigned short* Tl  = (unsigned short*)(wsf + p); p += 528384;   // 2.1 MB
    unsigned short* Tfh = (unsigned short*)(wsf + p); p += 573440;   // 2.3 MB (fwd trig hi, frag-ordered)
    unsigned short* Tfl = (unsigned short*)(wsf + p); p += 573440;   // 2.3 MB
    float*  wt   = wsf + p; p += 1572864;                            // 6.3 MB transposed W
    unsigned short* wbh = (unsigned short*)(wsf + p); p += 2097152;  // 8.4 MB W_big hi (frag-ordered)
    unsigned short* wbl = (unsigned short*)(wsf + p); p += 2097152;  // 8.4 MB W_big lo
    float*  xt0  = wsf + p; p += 2048;
    float*  rb0  = wsf + p; p += 4194304;
    float*  rb1  = wsf + p; p += 8388608;
    float*  xfpf = wsf + p; p += 12582912;                           // 50 MB partials (levels 0..2)
    unsigned* pv = (unsigned*)(wsf + p); p += 34078720;              // 136 MB packed V (frag-ordered)
    (void)ws_size; (void)in_sizes; (void)n_in; (void)out_size;

    size_t udo[13], uso[13];
    for (int i = 0; i < 13; i++) {
        udo[i] = 33554432ull - (16777216u >> i);
        uso[i] = 50329600ull - (16777216u >> i);
    }
    const int kbs_h[5] = {128,64,32,16,8};
    const int pvp_h[5] = {0,128,192,224,240};

    // tables (independent of data chain): trig, W transpose, big mixing matrix
    gen_tbl2_k<<<dim3(2048, 13, 2), 256, 0, stream>>>(Th, Tl, Tfh, Tfl);
    wtr_k<<<dim3(64, 6), 256, 0, stream>>>(wAr, wAi, wBr, wBi, wCr, wCi, wt);
    wbig_k<<<dim3(64, 32), 256, 0, stream>>>(wt, wbh, wbl);

    // decomposition: big levels 0..4 (emit s fp32 + packed pv), levels 5..12 + T0 fused
    for (int i = 0; i < 5; i++) {
        int nh = 4096 >> i;
        const float* xin_l = (i == 0) ? x : (out + uso[i-1]);
        decomp_k<<<dim3(nh/128, BB), 256, 0, stream>>>(xin_l, ecd, ecs,
                out + uso[i], pv + (size_t)pvp_h[i]*131072, nh, kbs_h[i]);
    }
    decomp_small_k<<<BB, 256, 0, stream>>>(out + uso[4], ecd, ecs, T0w, T0b, pv, xt0);

    // spectral pipeline: fwd(MFMA, split-K) -> reduce(lvls 0..2) -> mix(MFMA) -> inv(MFMA)
    fft_fwd_mfma_k<<<dim3(24, BB), 256, 0, stream>>>(pv, Tfh, Tfl, xfpf, xf_all);
    reduce_fwd_k<<<dim3(1024, 3), 256, 0, stream>>>(xfpf, xf_all);
    mix_mfma_k<<<454, 256, 0, stream>>>(xf_all, wbh, wbl, ofp);
    fft_inv_mfma_k<<<dim3(133, BB), 256, 0, stream>>>(ofp, Th, Tl, out);

    // reconstruction: levels 12..6 fused (output -> rb0), then big levels 5..0
    recon_small_k<<<BB, 256, 0, stream>>>(xt0, out, rce, rco, rb0);
    const float* rin = rb0;
    for (int i = 5; i >= 0; i--) {
        int nh = 4096 >> i;
        float* ro = (i == 0) ? out : ((i & 1) ? rb1 : rb0);
        int tot = BB * nh * CC;
        recon_k<<<(tot + 255)/256, 256, 0, stream>>>(rin, out + uso[i], out + udo[i], rce, rco, ro, nh);
        rin = ro;
    }
}

// Round 17
// 420.004 us; speedup vs baseline: 1.4891x; 1.1830x over previous
//
#include <hip/hip_runtime.h>

#define BB 32
#define CKD 64
#define CC 8
#define KK 8
#define FPW 132   // u32 pitch for fwd V-staging

// level tables (compile-time; N=8192, 13 levels)
__device__ const int D_FCB[14] = {0,32,48,56,60,62,63,64,65,66,67,68,69,70};  // fwd 128-t chunk prefix
__device__ const int D_TB[14] = {0,64,96,112,120,124,126,127,128,129,130,131,132,133}; // inv 64-t tile prefix
__device__ const int D_FTOF[13] = {0,524288,786432,917504,983040,1015808,1032192,
                                   1048576,1064960,1081344,1097728,1114112,1130496}; // fwd table elem offsets
// mix x-major prefix
__device__ const int D_XP[65] = {0,13,25,36,46,56,65,74,83,92,100,108,116,124,132,140,
    148,156,163,170,177,184,191,198,205,212,219,226,233,240,247,254,261,268,274,280,
    286,292,298,304,310,316,322,328,334,340,346,352,358,364,370,376,382,388,394,400,
    406,412,418,424,430,436,442,448,454};

typedef __attribute__((ext_vector_type(4))) short s4v;
typedef __attribute__((ext_vector_type(8))) short s8v;
typedef __attribute__((ext_vector_type(4))) float f4v;

static __device__ __forceinline__ float4 ld4(const float* p){ return *(const float4*)p; }
static __device__ __forceinline__ size_t d_udo(int i){ return 33554432ull - (16777216u >> i); }
static __device__ __forceinline__ size_t d_uso(int i){ return 50329600ull - (16777216u >> i); }
static __device__ __forceinline__ size_t d_tof(int i){ return 128ull * (8192u - (8192u >> i)); }

static __device__ __forceinline__ unsigned short b16(float f) {
    unsigned u = __float_as_uint(f);
    u += 0x7FFFu + ((u >> 16) & 1u);      // RNE
    return (unsigned short)(u >> 16);
}
static __device__ __forceinline__ float fb16(unsigned short h) {
    return __uint_as_float(((unsigned)h) << 16);
}
static __device__ __forceinline__ unsigned packhl(float f) {
    unsigned u = __float_as_uint(f);
    unsigned hi = u & 0xFFFF0000u;        // truncation split
    float r = f - __uint_as_float(hi);
    unsigned lo = __float_as_uint(r) & 0xFFFF0000u;
    return (hi >> 16) | lo;
}

// ---------------- combined trig-table generation (z=0: inv T, z=1: fwd F frag-ordered)
__global__ __launch_bounds__(256) void gen_tbl2_k(unsigned short* __restrict__ Th,
        unsigned short* __restrict__ Tl, unsigned short* __restrict__ Tfh,
        unsigned short* __restrict__ Tfl) {
    int lvl = blockIdx.y;
    int nh = 4096 >> lvl;
    int idx = blockIdx.x * 256 + threadIdx.x;
    if (blockIdx.z == 0) {
        if (idx >= nh * 128) return;
        int t = idx >> 7, k = idx & 127, x = k >> 1;
        int l = nh / 2 + 1; if (l > 64) l = 64;
        float v = 0.f;
        if (x < l) {
            int r = (x * t) & (nh - 1);
            float th = 6.283185307179586f * ((float)r / (float)nh);
            float s, c; sincosf(th, &s, &c);
            v = (k & 1) ? s : c;
        }
        unsigned short hi = b16(v);
        unsigned short lo = b16(v - fb16(hi));
        size_t off = d_tof(lvl) + idx;
        Th[off] = hi; Tl[off] = lo;
    } else {
        int nhp = nh < 128 ? 128 : nh;
        if (idx >= 128 * nhp) return;
        int j = idx & 7;
        int lane = (idx >> 3) & 63;
        int mt = (idx >> 9) & 7;
        int kb = idx >> 12;
        int row = mt*16 + (lane & 15);
        int t = kb*32 + (lane >> 4)*8 + j;
        int x = row >> 1;
        int l = nh / 2 + 1; if (l > 64) l = 64;
        float v = 0.f;
        if (x < l && t < nh) {
            int r = (x * t) & (nh - 1);
            float th = 6.283185307179586f * ((float)r / (float)nh);
            float s, c; sincosf(th, &s, &c);
            v = (row & 1) ? -s : c;
        }
        unsigned short hi = b16(v);
        unsigned short lo = b16(v - fb16(hi));
        size_t off = (size_t)D_FTOF[lvl] + idx;
        Tfh[off] = hi; Tfl[off] = lo;
    }
}

// ---------------- W transpose: wt[arr][x][i*64+o] = W_arr[(i*64+o)*64 + x]
__global__ __launch_bounds__(256) void wtr_k(const float* __restrict__ wAr,
        const float* __restrict__ wAi, const float* __restrict__ wBr,
        const float* __restrict__ wBi, const float* __restrict__ wCr,
        const float* __restrict__ wCi, float* __restrict__ wt) {
    int x = blockIdx.x, arr = blockIdx.y;
    const float* W;
    switch (arr) {
        case 0: W = wAr; break;
        case 1: W = wAi; break;
        case 2: W = wBr; break;
        case 3: W = wBi; break;
        case 4: W = wCr; break;
        default: W = wCi; break;
    }
    float* o = wt + ((size_t)arr*64 + x)*4096;
    for (int q = threadIdx.x; q < 4096; q += 256)
        o[q] = W[(size_t)q*64 + x];
}

// ---------------- big mixing matrix, FRAGMENT-ORDERED bf16 hi/lo, signs/zeros folded.
__global__ __launch_bounds__(256) void wbig_k(const float* __restrict__ wt,
        unsigned short* __restrict__ wbh, unsigned short* __restrict__ wbl) {
    int x = blockIdx.x;
    int f0 = blockIdx.y * 2048;
    for (int q = threadIdx.x; q < 2048; q += 256) {
        int f = f0 + q;
        int j = f & 7;
        int lane = (f >> 3) & 63;
        int nt = (f >> 9) & 15;
        int kt = f >> 13;
        int k = kt*32 + (lane >> 4)*8 + j;
        int n = nt*16 + (lane & 15);
        int pk = k >> 6, i = k & 63;
        int pn = n >> 6, o = n & 63;
        int arr; float sgn;
        switch ((pn << 2) | pk) {
            case 0:  arr = 0; sgn =  1.f; break;
            case 1:  arr = 1; sgn = -1.f; break;
            case 2:  arr = 2; sgn =  1.f; break;
            case 3:  arr = 3; sgn = -1.f; break;
            case 4:  arr = 1; sgn = -1.f; break;
            case 5:  arr = 0; sgn = -1.f; break;
            case 6:  arr = 3; sgn = -1.f; break;
            case 7:  arr = 2; sgn = -1.f; break;
            case 8:  arr = 4; sgn =  1.f; break;
            case 9:  arr = 5; sgn = -1.f; break;
            case 12: arr = 5; sgn = -1.f; break;
            case 13: arr = 4; sgn = -1.f; break;
            default: arr = -1; sgn = 0.f; break;
        }
        float v = 0.f;
        if (arr >= 0) v = sgn * wt[((size_t)arr*64 + x)*4096 + (size_t)i*64 + o];
        unsigned short h = b16(v);
        unsigned short l2 = b16(v - fb16(h));
        wbh[(size_t)x*65536 + f] = h;
        wbl[(size_t)x*65536 + f] = l2;
    }
}

// ---------------- decompose (big levels 0..4)
__global__ __launch_bounds__(256) void decomp_k(const float* __restrict__ xin,
        const float* __restrict__ ecd, const float* __restrict__ ecs,
        float* __restrict__ dslot, float* __restrict__ sslot, int nh) {
    int idx = blockIdx.x * 256 + threadIdx.x;
    if (idx >= BB * nh * CC) return;
    int c = idx & 7;
    int t = (idx >> 3) % nh;
    int b = idx / (nh * CC);
    const float* p0 = xin + ((size_t)b * 2 * nh + 2 * t) * CKD + c * KK;
    float xa[16];
    float4 v;
    v = ld4(p0);      xa[0]=v.x; xa[1]=v.y; xa[2]=v.z; xa[3]=v.w;
    v = ld4(p0+4);    xa[4]=v.x; xa[5]=v.y; xa[6]=v.z; xa[7]=v.w;
    v = ld4(p0+64);   xa[8]=v.x; xa[9]=v.y; xa[10]=v.z; xa[11]=v.w;
    v = ld4(p0+68);   xa[12]=v.x; xa[13]=v.y; xa[14]=v.z; xa[15]=v.w;
    float dd[8], ss[8];
    #pragma unroll
    for (int m = 0; m < 8; m++) { dd[m] = 0.f; ss[m] = 0.f; }
    #pragma unroll
    for (int j = 0; j < 16; j++) {
        float xv = xa[j];
        #pragma unroll
        for (int m = 0; m < 8; m++) {
            dd[m] = fmaf(xv, ecd[j*8+m], dd[m]);
            ss[m] = fmaf(xv, ecs[j*8+m], ss[m]);
        }
    }
    size_t ob = ((size_t)b * nh + t) * CKD + c * KK;
    *(float4*)(dslot+ob)   = make_float4(dd[0],dd[1],dd[2],dd[3]);
    *(float4*)(dslot+ob+4) = make_float4(dd[4],dd[5],dd[6],dd[7]);
    *(float4*)(sslot+ob)   = make_float4(ss[0],ss[1],ss[2],ss[3]);
    *(float4*)(sslot+ob+4) = make_float4(ss[4],ss[5],ss[6],ss[7]);
}

// ---------------- fused decompose levels 5..12 + T0 linear; one block per b
__global__ __launch_bounds__(256) void decomp_small_k(const float* __restrict__ s4base,
        const float* __restrict__ ecd, const float* __restrict__ ecs,
        const float* __restrict__ T0w, const float* __restrict__ T0b,
        float* __restrict__ outbuf, float* __restrict__ xt0) {
    __shared__ float sA[128*64];   // 32 KB
    __shared__ float sB[64*64];    // 16 KB
    int b = blockIdx.x, tid = threadIdx.x;
    for (int lvl = 5; lvl <= 12; lvl++) {
        int nh = 4096 >> lvl;
        const float* src = (lvl == 5) ? (s4base + (size_t)b*256*CKD)
                                      : (((lvl - 6) & 1) ? sB : sA);
        float* dst = ((lvl - 5) & 1) ? sB : sA;
        float* dG = outbuf + d_udo(lvl) + (size_t)b*nh*CKD;
        float* sG = outbuf + d_uso(lvl) + (size_t)b*nh*CKD;
        for (int q = tid; q < nh*8; q += 256) {
            int c = q & 7, t = q >> 3;
            const float* p0 = src + (size_t)(2*t)*CKD + c*KK;
            float xa[16];
            float4 v;
            v = ld4(p0);      xa[0]=v.x; xa[1]=v.y; xa[2]=v.z; xa[3]=v.w;
            v = ld4(p0+4);    xa[4]=v.x; xa[5]=v.y; xa[6]=v.z; xa[7]=v.w;
            v = ld4(p0+64);   xa[8]=v.x; xa[9]=v.y; xa[10]=v.z; xa[11]=v.w;
            v = ld4(p0+68);   xa[12]=v.x; xa[13]=v.y; xa[14]=v.z; xa[15]=v.w;
            float dd[8], ss[8];
            #pragma unroll
            for (int m = 0; m < 8; m++) { dd[m] = 0.f; ss[m] = 0.f; }
            #pragma unroll
            for (int j = 0; j < 16; j++) {
                float xv = xa[j];
                #pragma unroll
                for (int m = 0; m < 8; m++) {
                    dd[m] = fmaf(xv, ecd[j*8+m], dd[m]);
                    ss[m] = fmaf(xv, ecs[j*8+m], ss[m]);
                }
            }
            size_t ob = (size_t)t * CKD + c * KK;
            *(float4*)(dG+ob)   = make_float4(dd[0],dd[1],dd[2],dd[3]);
            *(float4*)(dG+ob+4) = make_float4(dd[4],dd[5],dd[6],dd[7]);
            *(float4*)(sG+ob)   = make_float4(ss[0],ss[1],ss[2],ss[3]);
            *(float4*)(sG+ob+4) = make_float4(ss[4],ss[5],ss[6],ss[7]);
            float* dl = dst + t*CKD + c*KK;
            #pragma unroll
            for (int j = 0; j < 8; j++) dl[j] = ss[j];
        }
        __syncthreads();
    }
    // T0 linear on s12 (row 0 of sB)
    if (tid < 64) {
        int m = tid & 7, c = tid >> 3;
        const float* xr = sB + c*KK;
        float a = T0b[m];
        #pragma unroll
        for (int j = 0; j < 8; j++) a = fmaf(xr[j], T0w[m*8+j], a);
        xt0[(size_t)b*64 + tid] = a;
    }
}

// ---------------- forward truncated DFT via MFMA, z-MERGED (N=128 = 2z x 64i).
__global__ __launch_bounds__(256) void fft_fwd_mfma_k(const float* __restrict__ outbuf,
        const unsigned short* __restrict__ Tfh, const unsigned short* __restrict__ Tfl,
        float* __restrict__ xfpf, float2* __restrict__ xf_all) {
    __shared__ unsigned vp[128*FPW];   // 67.6 KB packed bf16 hi/lo [(z,i)][t]
    int slot = blockIdx.x;
    int lvl = 0;
    while (lvl < 12 && slot >= D_FCB[lvl+1]) lvl++;
    int nh = 4096 >> lvl;
    int ch = D_FCB[lvl+1] - D_FCB[lvl];
    int t0s = (slot - D_FCB[lvl]) * 128;
    int b = blockIdx.y;
    const float* V0 = outbuf + d_udo(lvl) + (size_t)b * nh * CKD;
    const float* V1 = outbuf + d_uso(lvl) + (size_t)b * nh * CKD;
    const unsigned short* THb = Tfh + D_FTOF[lvl];
    const unsigned short* TLb = Tfl + D_FTOF[lvl];
    int tid = threadIdx.x;
    int w = tid >> 6, lane = tid & 63;
    int col = lane & 15, khi = lane >> 4;
    int mt0 = w * 2;                        // wave handles m-tiles {2w, 2w+1}
    #pragma unroll
    for (int q = 0; q < 16; q++) {
        int fi = tid + 256*q;               // 4096 float4 = 128 t x 32 quads
        int tl_ = fi >> 5;
        int t = t0s + tl_;
        int iq = fi & 31;
        int z = iq >> 4;
        int i4 = (iq & 15) * 4;
        const float* Vz = z ? V1 : V0;
        float4 v = make_float4(0.f,0.f,0.f,0.f);
        if (t < nh) v = ld4(Vz + (size_t)t*CKD + i4);
        const float* pv = &v.x;
        int rowb = z*64 + i4;
        #pragma unroll
        for (int j = 0; j < 4; j++) {
            int row = rowb + j;
            int cw = tl_ ^ (((row >> 3) & 7) << 2);   // block-XOR swizzle
            vp[row*FPW + cw] = packhl(pv[j]);
        }
    }
    __syncthreads();
    int rrow[8], rswz[8];
    #pragma unroll
    for (int n = 0; n < 8; n++) {
        rrow[n] = n*16 + col;
        rswz[n] = ((rrow[n] >> 3) & 7) << 2;
    }
    f4v acc[2][8];
    #pragma unroll
    for (int m = 0; m < 2; m++)
        #pragma unroll
        for (int n = 0; n < 8; n++) acc[m][n] = (f4v){0.f,0.f,0.f,0.f};
    int kb0 = (slot - D_FCB[lvl]) * 4;
    #pragma unroll
    for (int kk = 0; kk < 4; kk++) {
        int kb = kb0 + kk;
        s8v ah[2], al[2];
        #pragma unroll
        for (int m = 0; m < 2; m++) {
            size_t fo = (((size_t)kb*8 + (mt0 + m))*64 + lane)*8;   // lane-contiguous
            ah[m] = *(const s8v*)(THb + fo);
            al[m] = *(const s8v*)(TLb + fo);
        }
        int cb = kk*32 + khi*8;
        #pragma unroll
        for (int n = 0; n < 8; n++) {
            const unsigned* pr = vp + rrow[n]*FPW;
            uint4 w0 = *(const uint4*)(pr + (cb ^ rswz[n]));
            uint4 w1 = *(const uint4*)(pr + ((cb + 4) ^ rswz[n]));
            s8v bh, bl;
            const unsigned* pw = &w0.x;
            #pragma unroll
            for (int j = 0; j < 4; j++) {
                bh[j] = (short)(pw[j] & 0xFFFFu);
                bl[j] = (short)(pw[j] >> 16);
            }
            pw = &w1.x;
            #pragma unroll
            for (int j = 0; j < 4; j++) {
                bh[4+j] = (short)(pw[j] & 0xFFFFu);
                bl[4+j] = (short)(pw[j] >> 16);
            }
            #pragma unroll
            for (int m = 0; m < 2; m++) {
                acc[m][n] = __builtin_amdgcn_mfma_f32_16x16x32_bf16(ah[m], bh, acc[m][n], 0,0,0);
                acc[m][n] = __builtin_amdgcn_mfma_f32_16x16x32_bf16(ah[m], bl, acc[m][n], 0,0,0);
                acc[m][n] = __builtin_amdgcn_mfma_f32_16x16x32_bf16(al[m], bh, acc[m][n], 0,0,0);
            }
        }
    }
    if (ch == 1) {
        float* XB = (float*)xf_all + (size_t)lvl*524288 + (size_t)b*16384;
        #pragma unroll
        for (int m = 0; m < 2; m++) {
            int m0 = (mt0 + m)*16 + khi*4;
            #pragma unroll
            for (int n = 0; n < 8; n++) {
                int ic = n*16 + col;
                int z = ic >> 6, i = ic & 63;
                float* X = XB + (size_t)z*8192;
                #pragma unroll
                for (int r = 0; r < 4; r++) {
                    int row = m0 + r;
                    X[(((size_t)(row >> 1)*64 + i) << 1) | (row & 1)] = acc[m][n][r];
                }
            }
        }
    } else {
        #pragma unroll
        for (int m = 0; m < 2; m++) {
            int m0 = (mt0 + m)*16 + khi*4;
            #pragma unroll
            for (int n = 0; n < 8; n++) {
                int ic = n*16 + col;
                int z = ic >> 6, i = ic & 63;
                float* P = xfpf + ((size_t)slot*64 + (size_t)b*2 + z) * 8192;
                #pragma unroll
                for (int r = 0; r < 4; r++)
                    P[(size_t)(m0 + r)*64 + i] = acc[m][n][r];
            }
        }
    }
}

// ---------------- sum fwd partials (levels 0..4), relayout -> xf_all float2
__global__ __launch_bounds__(256) void reduce_fwd_k(const float* __restrict__ xfpf,
        float2* __restrict__ xf_all) {
    int lvl = blockIdx.y;
    int e = blockIdx.x * 256 + threadIdx.x;   // < 64*4096
    int j = e & 4095;
    int bz = e >> 12;
    int x = j >> 6, i = j & 63;
    int c0 = D_FCB[lvl], c1 = D_FCB[lvl+1];
    float re = 0.f, im = 0.f;
    for (int c = c0; c < c1; c++) {
        size_t base = ((size_t)c*64 + bz) * 8192;
        re += xfpf[base + (size_t)(2*x)*64 + i];
        im += xfpf[base + (size_t)(2*x+1)*64 + i];
    }
    xf_all[(size_t)lvl*262144 + (size_t)bz*4096 + j] = make_float2(re, im);
}

// ---------------- spectral mix via MFMA: block = (x-major, lvl); 256 thr = 4 waves.
// output PACKED u32 (hi | lo<<16).
__global__ __launch_bounds__(256) void mix_mfma_k(const float2* __restrict__ xf_all,
        const unsigned short* __restrict__ wbh, const unsigned short* __restrict__ wbl,
        unsigned* __restrict__ ofp) {
    __shared__ unsigned ax[32*260];   // 33.3 KB packed bf16 hi/lo X [b][k], XOR swizzled
    int x = 0;
    while (x < 64 && (int)blockIdx.x >= D_XP[x+1]) x++;
    int lvl = blockIdx.x - D_XP[x];
    int nh = 4096 >> lvl;
    const float2* xfL = xf_all + (size_t)lvl*262144;
    int tid = threadIdx.x;
    for (int q = tid; q < 4096; q += 256) {
        int b = q >> 7, z = (q >> 6) & 1, i = q & 63;
        float2 v = xfL[((size_t)b*2 + z)*4096 + (size_t)x*64 + i];
        int sw = ((b >> 3) & 7) << 2;
        int kR = z*128 + i;
        ax[b*260 + (kR ^ sw)] = packhl(v.x);
        ax[b*260 + ((kR + 64) ^ sw)] = packhl(v.y);
    }
    __syncthreads();
    int w4 = tid >> 6, lane = tid & 63;
    int col = lane & 15, khi = lane >> 4;
    int mt = w4 & 1, nt0 = (w4 >> 1) * 8;
    int arow = mt*16 + col;
    int asw = ((arow >> 3) & 7) << 2;
    const unsigned* ap = ax + arow*260;
    const unsigned short* WBH = wbh + (size_t)x*65536;
    const unsigned short* WBL = wbl + (size_t)x*65536;
    f4v acc[8];
    #pragma unroll
    for (int n = 0; n < 8; n++) acc[n] = (f4v){0.f,0.f,0.f,0.f};
    #pragma unroll
    for (int kt = 0; kt < 8; kt++) {
        int cb = kt*32 + khi*8;
        uint4 a0 = *(const uint4*)(ap + (cb ^ asw));
        uint4 a1 = *(const uint4*)(ap + ((cb + 4) ^ asw));
        s8v ah, al;
        const unsigned* pw = &a0.x;
        #pragma unroll
        for (int j = 0; j < 4; j++) {
            ah[j] = (short)(pw[j] & 0xFFFFu);
            al[j] = (short)(pw[j] >> 16);
        }
        pw = &a1.x;
        #pragma unroll
        for (int j = 0; j < 4; j++) {
            ah[4+j] = (short)(pw[j] & 0xFFFFu);
            al[4+j] = (short)(pw[j] >> 16);
        }
        #pragma unroll
        for (int n = 0; n < 8; n++) {
            int nt = nt0 + n;
            size_t fo = (((size_t)kt*16 + nt)*64 + lane)*8;
            s8v bh = *(const s8v*)(WBH + fo);
            s8v bl = *(const s8v*)(WBL + fo);
            acc[n] = __builtin_amdgcn_mfma_f32_16x16x32_bf16(ah, bh, acc[n], 0, 0, 0);
            acc[n] = __builtin_amdgcn_mfma_f32_16x16x32_bf16(ah, bl, acc[n], 0, 0, 0);
            acc[n] = __builtin_amdgcn_mfma_f32_16x16x32_bf16(al, bh, acc[n], 0, 0, 0);
        }
    }
    float wfac = (x == 0 || 2*x == nh) ? 1.f : 2.f;   // irfft doubling; DC/Nyquist not doubled
    float sc = wfac / (float)nh;
    int k0 = 2*x;
    #pragma unroll
    for (int n = 0; n < 8; n++) {
        int nn = nt0 + n;
        int pn = nn >> 2;              // 0:udRe 1:ud(-Im) 2:usRe 3:us(-Im)
        int o = (nn & 3)*16 + col;
        int z = pn >> 1;
        int kr = k0 + (pn & 1);
        #pragma unroll
        for (int r = 0; r < 4; r++) {
            int b = mt*16 + khi*4 + r;
            size_t base = (((size_t)lvl*32 + b)*2 + z)*8192 + (size_t)kr*64 + o;
            ofp[base] = packhl(sc * acc[n][r]);
        }
    }
}

// ---------------- inverse truncated DFT via MFMA, z-MERGED, packed-G staging.
__global__ __launch_bounds__(256) void fft_inv_mfma_k(
        const unsigned* __restrict__ ofp,
        const unsigned short* __restrict__ Th,  const unsigned short* __restrict__ Tl,
        float* __restrict__ outbuf) {
    __shared__ unsigned gp[2*64*132];   // [z][o][k] packed u32 (67.6 KB)
    int lvl = 0;
    while (lvl < 12 && (int)blockIdx.x >= D_TB[lvl+1]) lvl++;
    int g = blockIdx.x - D_TB[lvl];
    int nh = 4096 >> lvl;
    int tbase = g * 64;
    int b = blockIdx.y;
    int tid = threadIdx.x;
    const unsigned* Gp = ofp + (((size_t)lvl*32 + b)*2)*8192;
    #pragma unroll
    for (int q = 0; q < 16; q++) {
        int fi = tid + 256*q;          // 0..4095, uint4 granules
        int z = fi >> 11;
        int rem = fi & 2047;
        int k = rem >> 4, o4 = (rem & 15)*4;
        uint4 v = *(const uint4*)(Gp + (size_t)z*8192 + (size_t)k*64 + o4);
        const unsigned* pw = &v.x;
        #pragma unroll
        for (int i = 0; i < 4; i++)
            gp[z*8448 + (o4+i)*132 + k] = pw[i];
    }
    __syncthreads();
    int w = tid >> 6;
    int lane = tid & 63;
    int tb = tbase + w*16;
    if (tb >= nh) return;
    int trow = lane & 15, khi = lane >> 4;
    int tA = tb + trow; if (tA >= nh) tA = nh - 1;    // clamp (stores guarded)
    const unsigned short* THp = Th + d_tof(lvl) + (size_t)tA*128 + khi*8;
    const unsigned short* TLp = Tl + d_tof(lvl) + (size_t)tA*128 + khi*8;
    f4v acc[8];
    #pragma unroll
    for (int n = 0; n < 8; n++) acc[n] = (f4v){0.f,0.f,0.f,0.f};
    #pragma unroll
    for (int kk = 0; kk < 4; kk++) {
        s8v ah = *(const s8v*)(THp + kk*32);
        s8v al = *(const s8v*)(TLp + kk*32);
        #pragma unroll
        for (int n = 0; n < 8; n++) {
            int z = n >> 2;
            int off = z*8448 + ((n & 3)*16 + trow)*132 + kk*32 + khi*8;
            uint4 w0 = *(const uint4*)(gp + off);
            uint4 w1 = *(const uint4*)(gp + off + 4);
            s8v bh, bl;
            const unsigned* pw = &w0.x;
            #pragma unroll
            for (int j = 0; j < 4; j++) {
                bh[j] = (short)(pw[j] & 0xFFFFu);
                bl[j] = (short)(pw[j] >> 16);
            }
            pw = &w1.x;
            #pragma unroll
            for (int j = 0; j < 4; j++) {
                bh[4+j] = (short)(pw[j] & 0xFFFFu);
                bl[4+j] = (short)(pw[j] >> 16);
            }
            acc[n] = __builtin_amdgcn_mfma_f32_16x16x32_bf16(ah, bh, acc[n], 0, 0, 0);
            acc[n] = __builtin_amdgcn_mfma_f32_16x16x32_bf16(ah, bl, acc[n], 0, 0, 0);
            acc[n] = __builtin_amdgcn_mfma_f32_16x16x32_bf16(al, bh, acc[n], 0, 0, 0);
        }
    }
    float* U0 = outbuf + d_udo(lvl) + (size_t)b * nh * CKD;
    float* U1 = outbuf + d_uso(lvl) + (size_t)b * nh * CKD;
    int thi4 = khi * 4;
    #pragma unroll
    for (int n = 0; n < 8; n++) {
        float* U = (n >> 2) ? U1 : U0;
        int ocol = (n & 3)*16 + trow;
        #pragma unroll
        for (int r = 0; r < 4; r++) {
            int t = tb + thi4 + r;
            if (t < nh) U[(size_t)t*64 + ocol] = acc[n][r];
        }
    }
}

// ---------------- fused reconstruction levels 12..6; one block per b; x stays in LDS
__global__ __launch_bounds__(256) void recon_small_k(const float* __restrict__ xt0,
        const float* __restrict__ outbuf,
        const float* __restrict__ rce, const float* __restrict__ rco,
        float* __restrict__ rb0) {
    __shared__ float xA[128*64];   // 32 KB
    __shared__ float xB[64*64];    // 16 KB
    int b = blockIdx.x, tid = threadIdx.x;
    if (tid < 64) xB[tid] = xt0[(size_t)b*64 + tid];
    __syncthreads();
    for (int i = 12; i >= 6; i--) {
        int nh = 4096 >> i;
        const float* cur = ((i == 12) || !(i & 1)) ? xB : xA;
        float* nxt = (i & 1) ? xB : xA;
        const float* Us = outbuf + d_uso(i) + (size_t)b*nh*CKD;
        const float* Ud = outbuf + d_udo(i) + (size_t)b*nh*CKD;
        for (int q = tid; q < nh*8; q += 256) {
            int c = q & 7, t = q >> 3;
            size_t base = (size_t)t*CKD + c*KK;
            float xc[16];
            float4 a0 = ld4(cur+base), a1 = ld4(cur+base+4);
            float4 u0 = ld4(Us+base),  u1 = ld4(Us+base+4);
            float4 d0 = ld4(Ud+base),  d1 = ld4(Ud+base+4);
            xc[0]=a0.x+u0.x; xc[1]=a0.y+u0.y; xc[2]=a0.z+u0.z; xc[3]=a0.w+u0.w;
            xc[4]=a1.x+u1.x; xc[5]=a1.y+u1.y; xc[6]=a1.z+u1.z; xc[7]=a1.w+u1.w;
            xc[8]=d0.x;  xc[9]=d0.y;  xc[10]=d0.z; xc[11]=d0.w;
            xc[12]=d1.x; xc[13]=d1.y; xc[14]=d1.z; xc[15]=d1.w;
            float e[8], o2[8];
            #pragma unroll
            for (int m = 0; m < 8; m++) { e[m] = 0.f; o2[m] = 0.f; }
            #pragma unroll
            for (int j = 0; j < 16; j++) {
                float xv = xc[j];
                #pragma unroll
                for (int m = 0; m < 8; m++) {
                    e[m]  = fmaf(xv, rce[j*8+m], e[m]);
                    o2[m] = fmaf(xv, rco[j*8+m], o2[m]);
                }
            }
            if (i > 6) {
                float* pe = nxt + (size_t)(2*t)*CKD + c*KK;
                #pragma unroll
                for (int j = 0; j < 8; j++) { pe[j] = e[j]; pe[CKD + j] = o2[j]; }
            } else {
                float* pe = rb0 + ((size_t)b*128 + 2*t)*CKD + c*KK;
                *(float4*)(pe)      = make_float4(e[0],e[1],e[2],e[3]);
                *(float4*)(pe+4)    = make_float4(e[4],e[5],e[6],e[7]);
                *(float4*)(pe+64)   = make_float4(o2[0],o2[1],o2[2],o2[3]);
                *(float4*)(pe+68)   = make_float4(o2[4],o2[5],o2[6],o2[7]);
            }
        }
        __syncthreads();
    }
}

// ---------------- reconstruct one big level: (x+Us, Ud) @ rc_e / rc_o, interleave
__global__ __launch_bounds__(256) void recon_k(const float* __restrict__ xin,
        const float* __restrict__ us, const float* __restrict__ ud,
        const float* __restrict__ rce, const float* __restrict__ rco,
        float* __restrict__ xout, int nh) {
    int idx = blockIdx.x*256 + threadIdx.x;
    if (idx >= BB*nh*CC) return;
    int c = idx & 7;
    int t = (idx >> 3) % nh;
    int b = idx / (nh*CC);
    size_t base = ((size_t)b*nh + t)*CKD + c*KK;
    float xc[16];
    float4 a0 = ld4(xin+base), a1 = ld4(xin+base+4);
    float4 u0 = ld4(us+base),  u1 = ld4(us+base+4);
    float4 d0 = ld4(ud+base),  d1 = ld4(ud+base+4);
    xc[0]=a0.x+u0.x; xc[1]=a0.y+u0.y; xc[2]=a0.z+u0.z; xc[3]=a0.w+u0.w;
    xc[4]=a1.x+u1.x; xc[5]=a1.y+u1.y; xc[6]=a1.z+u1.z; xc[7]=a1.w+u1.w;
    xc[8]=d0.x;  xc[9]=d0.y;  xc[10]=d0.z; xc[11]=d0.w;
    xc[12]=d1.x; xc[13]=d1.y; xc[14]=d1.z; xc[15]=d1.w;
    float e[8], o2[8];
    #pragma unroll
    for (int m = 0; m < 8; m++) { e[m] = 0.f; o2[m] = 0.f; }
    #pragma unroll
    for (int j = 0; j < 16; j++) {
        float xv = xc[j];
        #pragma unroll
        for (int m = 0; m < 8; m++) {
            e[m]  = fmaf(xv, rce[j*8+m], e[m]);
            o2[m] = fmaf(xv, rco[j*8+m], o2[m]);
        }
    }
    size_t ob = ((size_t)b*2*nh + 2*t)*CKD + c*KK;
    *(float4*)(xout+ob)      = make_float4(e[0],e[1],e[2],e[3]);
    *(float4*)(xout+ob+4)    = make_float4(e[4],e[5],e[6],e[7]);
    *(float4*)(xout+ob+64)   = make_float4(o2[0],o2[1],o2[2],o2[3]);
    *(float4*)(xout+ob+68)   = make_float4(o2[4],o2[5],o2[6],o2[7]);
}

extern "C" void kernel_launch(void* const* d_in, const int* in_sizes, int n_in,
                              void* d_out, int out_size, void* d_ws, size_t ws_size,
                              hipStream_t stream) {
    const float* x   = (const float*)d_in[0];
    const float* wAr = (const float*)d_in[1];
    const float* wAi = (const float*)d_in[2];
    const float* wBr = (const float*)d_in[3];
    const float* wBi = (const float*)d_in[4];
    const float* wCr = (const float*)d_in[5];
    const float* wCi = (const float*)d_in[6];
    const float* T0w = (const float*)d_in[7];
    const float* T0b = (const float*)d_in[8];
    const float* ecs = (const float*)d_in[9];
    const float* ecd = (const float*)d_in[10];
    const float* rce = (const float*)d_in[11];
    const float* rco = (const float*)d_in[12];
    float* out = (float*)d_out;
    float* wsf = (float*)d_ws;

    // workspace layout (floats)
    size_t p = 0;
    float2* xf_all = (float2*)(wsf + p); p += 6815744;               // 27 MB
    unsigned* ofp = (unsigned*)(wsf + p); p += 6815744;              // 27 MB packed G (hi|lo)
    unsigned short* Th  = (unsigned short*)(wsf + p); p += 528384;   // 2.1 MB (inv trig hi)
    unsigned short* Tl  = (unsigned short*)(wsf + p); p += 528384;   // 2.1 MB
    unsigned short* Tfh = (unsigned short*)(wsf + p); p += 573440;   // 2.3 MB (fwd trig hi, frag-ordered)
    unsigned short* Tfl = (unsigned short*)(wsf + p); p += 573440;   // 2.3 MB
    float*  wt   = wsf + p; p += 1572864;                            // 6.3 MB transposed W
    unsigned short* wbh = (unsigned short*)(wsf + p); p += 2097152;  // 8.4 MB W_big hi (frag-ordered)
    unsigned short* wbl = (unsigned short*)(wsf + p); p += 2097152;  // 8.4 MB W_big lo
    float*  xt0  = wsf + p; p += 2048;
    float*  rb0  = wsf + p; p += 4194304;
    float*  rb1  = wsf + p; p += 8388608;
    float*  xfpf = wsf + p; p += 36700160;                           // partials (levels 0..4 used)
    (void)ws_size; (void)in_sizes; (void)n_in; (void)out_size;

    size_t udo[13], uso[13];
    for (int i = 0; i < 13; i++) {
        udo[i] = 33554432ull - (16777216u >> i);
        uso[i] = 50329600ull - (16777216u >> i);
    }

    // tables (independent of data chain): trig, W transpose, big mixing matrix
    gen_tbl2_k<<<dim3(2048, 13, 2), 256, 0, stream>>>(Th, Tl, Tfh, Tfl);
    wtr_k<<<dim3(64, 6), 256, 0, stream>>>(wAr, wAi, wBr, wBi, wCr, wCi, wt);
    wbig_k<<<dim3(64, 32), 256, 0, stream>>>(wt, wbh, wbl);

    // decomposition: big levels 0..4 sequential, levels 5..12 + T0 fused
    for (int i = 0; i < 5; i++) {
        int nh = 4096 >> i;
        const float* xin_l = (i == 0) ? x : (out + uso[i-1]);
        int tot = BB * nh * CC;
        decomp_k<<<(tot + 255)/256, 256, 0, stream>>>(xin_l, ecd, ecs, out + udo[i], out + uso[i], nh);
    }
    decomp_small_k<<<BB, 256, 0, stream>>>(out + uso[4], ecd, ecs, T0w, T0b, out, xt0);

    // spectral pipeline: fwd(MFMA,z-merged) -> reduce(lvls 0..4) -> mix(MFMA) -> inv(MFMA)
    fft_fwd_mfma_k<<<dim3(70, BB), 256, 0, stream>>>(out, Tfh, Tfl, xfpf, xf_all);
    reduce_fwd_k<<<dim3(1024, 5), 256, 0, stream>>>(xfpf, xf_all);
    mix_mfma_k<<<454, 256, 0, stream>>>(xf_all, wbh, wbl, ofp);
    fft_inv_mfma_k<<<dim3(133, BB), 256, 0, stream>>>(ofp, Th, Tl, out);

    // reconstruction: levels 12..6 fused (output -> rb0), then big levels 5..0
    recon_small_k<<<BB, 256, 0, stream>>>(xt0, out, rce, rco, rb0);
    const float* rin = rb0;
    for (int i = 5; i >= 0; i--) {
        int nh = 4096 >> i;
        float* ro = (i == 0) ? out : ((i & 1) ? rb1 : rb0);
        int tot = BB * nh * CC;
        recon_k<<<(tot + 255)/256, 256, 0, stream>>>(rin, out + uso[i], out + udo[i], rce, rco, ro, nh);
        rin = ro;
    }
}